// Round 34
// baseline (568.157 us; speedup 1.0000x reference)
//
#include <hip/hip_runtime.h>
#include <math.h>

#define BN 2
#define HH 128
#define WW 160
#define HWn (HH*WW)          // 20480
#define CD 128
#define TT (BN*HWn)          // 40960 tokens per stream
#define TOKN ((size_t)TT*CD) // 5,242,880 elements

typedef __attribute__((ext_vector_type(8))) short bf16x8;
typedef __attribute__((ext_vector_type(4))) float f32x4;
typedef __attribute__((ext_vector_type(4))) unsigned short u16x4;

__device__ __forceinline__ float b2f(unsigned short s){
  unsigned u = ((unsigned)s) << 16;
  return __builtin_bit_cast(float, u);
}
__device__ __forceinline__ unsigned short f2b(float f){
  unsigned u = __builtin_bit_cast(unsigned, f);
  u = (u + 0x7fffu + ((u >> 16) & 1u)) >> 16;   // RNE
  return (unsigned short)u;
}

// ---------------- weight convert + (block 2112) tiny precompute ----------------
__global__ __launch_bounds__(256) void k_wconv(const float* __restrict__ attn_w,
      const float* __restrict__ ffn_w1, const float* __restrict__ ffn_w2,
      const float* __restrict__ cc_w, unsigned short* __restrict__ wt,
      const float* __restrict__ ref_proj, const float* __restrict__ src_i2w,
      const float* __restrict__ cam16,
      const float* __restrict__ bn1_g, const float* __restrict__ bn1_b,
      const float* __restrict__ fc1_w, const float* __restrict__ fc1_b,
      const float* __restrict__ fc2_w, const float* __restrict__ fc2_b,
      const float* __restrict__ ser_w, const float* __restrict__ ser_b,
      const float* __restrict__ see_w, const float* __restrict__ see_b,
      float* __restrict__ projsmall, float* __restrict__ gate){
  if (blockIdx.x == 2112){    // ---- small precompute: proj mats + SE gate ----
    __shared__ float mi[BN][16], t1[BN][128], t2[BN][128];
    int tid = threadIdx.x;
    const float inv_std = rsqrtf(1.0f + 1e-5f);
    if (tid < 32){
      int b = tid >> 4, idx = tid & 15, i = idx >> 2, k = idx & 3;
      float acc = 0.f;
      for (int j = 0; j < 4; j++) acc += ref_proj[b*16 + i*4 + j] * src_i2w[b*16 + j*4 + k];
      if (i < 3 && k < 3) projsmall[b*12 + i*3 + k] = acc;
      if (i < 3 && k == 3) projsmall[b*12 + 9 + i] = acc;
      mi[b][idx] = cam16[b*16 + idx] * inv_std * bn1_g[idx] + bn1_b[idx];
    }
    __syncthreads();
    int b = tid >> 7, c = tid & 127;
    float a = 0.f;
    for (int j = 0; j < 16; j++) a += mi[b][j] * fc1_w[j*128 + c];
    t1[b][c] = fmaxf(a + fc1_b[c], 0.f);
    __syncthreads();
    a = 0.f;
    for (int k = 0; k < 128; k++) a += t1[b][k] * fc2_w[k*128 + c];
    t2[b][c] = a + fc2_b[c];
    __syncthreads();
    a = 0.f;
    for (int k = 0; k < 128; k++) a += t2[b][k] * ser_w[k*128 + c];
    t1[b][c] = fmaxf(a + ser_b[c], 0.f);
    __syncthreads();
    a = 0.f;
    for (int k = 0; k < 128; k++) a += t1[b][k] * see_w[k*128 + c];
    a += see_b[c];
    gate[b*128 + c] = 1.f / (1.f + __expf(-a));
    return;
  }
  int i = blockIdx.x*256 + threadIdx.x;
  float v;
  if (i < 262144){                       // attn: [(l*4+m)][n][k] <- attn_w[lm][k][n]
    int k = i & 127, n = (i >> 7) & 127, lm = i >> 14;
    v = attn_w[((size_t)lm*128 + k)*128 + n];
  } else if (i < 393216){ int j = i - 262144;   // f1t: [l][n<256][k<128]
    int k = j & 127, n = (j >> 7) & 255, l = j >> 15;
    v = ffn_w1[((size_t)l*128 + k)*256 + n];
  } else if (i < 524288){ int j = i - 393216;   // f2t: [l][n<128][k<256]
    int k = j & 255, n = (j >> 8) & 127, l = j >> 15;
    v = ffn_w2[((size_t)l*256 + k)*128 + n];
  } else if (i < 540672){ int j = i - 524288;   // cct: [o][c] <- cc_w[c][o]
    int k = j & 127, n = j >> 7;
    v = cc_w[(size_t)k*128 + n];
  } else return;
  wt[i] = f2b(v);
}

// ---------------- K1: conv3x3(depth) + bn + relu + gate, pixel-major, bf16 out ----------------
__global__ __launch_bounds__(128) void k_hmap(const float* __restrict__ depth,
                       const float* __restrict__ rc_w, const float* __restrict__ rc_b,
                       const float* __restrict__ bn2_g, const float* __restrict__ bn2_b,
                       const float* __restrict__ gate, unsigned short* __restrict__ G){
  int bi = blockIdx.x; int n = bi / HWn; int p = bi - n*HWn;
  int y = p / WW, x = p - y*WW;
  int c = threadIdx.x;
  const float inv_std = rsqrtf(1.f + 1e-5f);
  float acc = 0.f;
#pragma unroll
  for (int ky = 0; ky < 3; ky++){
    int yy = y + ky - 1;
#pragma unroll
    for (int kx = 0; kx < 3; kx++){
      int xx = x + kx - 1;
      float v = (yy >= 0 && yy < HH && xx >= 0 && xx < WW) ? depth[n*HWn + yy*WW + xx] : 0.f;
      acc += v * rc_w[c*9 + ky*3 + kx];
    }
  }
  acc += rc_b[c];
  acc = fmaxf(acc * inv_std * bn2_g[c] + bn2_b[c], 0.f);
  G[(size_t)bi*128 + c] = f2b(acc * gate[n*128 + c]);
}

// ---- bf16 MFMA GEMM: 64 tokens/block (4 waves x 16), W staged in XOR-swizzled
// LDS in 128-col halves. acc[8] per wave. Section sec>0 reads A2 (cross QKV).
// Block (0,0) additionally zero-fills zfin[0..zn) (KVFIN for the next dispatch).
template<int K, int ACT, int LN>  // ACT: 1 relu, 2 elu+1 (where amask bit set)
__global__ __launch_bounds__(256) void k_bgemm6(
    const unsigned short* __restrict__ A, const unsigned short* __restrict__ A2, int ldA,
    const unsigned short* __restrict__ Wt,
    const float* __restrict__ bias, int amask,
    const unsigned short* __restrict__ resid,
    unsigned short* __restrict__ Cbase, size_t secStride, int ldC,
    const float* __restrict__ lng, const float* __restrict__ lnb,
    float* zfin, int zn){
  __shared__ unsigned short Wl[128*128];   // one 128-col half at a time, swizzled
  constexpr int NH = K/128;
  int tid = threadIdx.x;
  int wid = tid >> 6, lane = tid & 63;
  int sec = blockIdx.y;
  if (zfin && blockIdx.x == 0 && sec == 0){
    for (int i = tid; i < zn; i += 256) zfin[i] = 0.f;
  }
  const unsigned short* Ab = (sec == 0) ? A : A2;
  const unsigned short* Ws = Wt + (size_t)sec*128*K;
  const float* bs = bias + sec*128;
  unsigned short* C = Cbase + (size_t)sec*secStride;
  int r = lane & 15, ks = lane >> 4;
  size_t t0 = (size_t)blockIdx.x*64 + wid*16;
  const unsigned short* ap = Ab + (t0 + r)*ldA + ks*8;
  f32x4 acc[8] = {};
#pragma unroll
  for (int hh = 0; hh < NH; hh++){
    if (hh > 0) __syncthreads();
    // stage 128x128 half, swizzle c8 -> c8 ^ (row&7)
#pragma unroll
    for (int i = 0; i < 8; i++){
      int idx = i*256 + tid;
      int row = idx >> 4, c8 = idx & 15;
      int c8s = c8 ^ (row & 7);
      *(bf16x8*)&Wl[row*128 + c8s*8] = *(const bf16x8*)(Ws + (size_t)row*K + hh*128 + c8*8);
    }
    __syncthreads();
#pragma unroll
    for (int j = 0; j < 4; j++){
      bf16x8 a = *(const bf16x8*)(ap + hh*128 + j*32);
#pragma unroll
      for (int f = 0; f < 8; f++){
        int row = f*16 + r;
        int c8s = (j*4 + ks) ^ (row & 7);
        bf16x8 w = *(const bf16x8*)&Wl[row*128 + c8s*8];
        acc[f] = __builtin_amdgcn_mfma_f32_16x16x32_bf16(w, a, acc[f], 0, 0, 0);
      }
    }
  }
  bool act = (amask >> sec) & 1;
  size_t trow = t0 + r;
  float vv[8][4];
#pragma unroll
  for (int f = 0; f < 8; f++){
    float4 bi4 = *(const float4*)&bs[f*16 + 4*ks];
    vv[f][0] = acc[f][0] + bi4.x; vv[f][1] = acc[f][1] + bi4.y;
    vv[f][2] = acc[f][2] + bi4.z; vv[f][3] = acc[f][3] + bi4.w;
    if (resid){
      u16x4 rr = *(const u16x4*)(resid + trow*128 + f*16 + 4*ks);
#pragma unroll
      for (int e = 0; e < 4; e++) vv[f][e] += b2f(rr[e]);
    }
    if (act){
#pragma unroll
      for (int e = 0; e < 4; e++){
        float x = vv[f][e];
        if (ACT == 1) x = fmaxf(x, 0.f);
        if (ACT == 2) x = x > 0.f ? x + 1.f : __expf(x);
        vv[f][e] = x;
      }
    }
  }
  if (LN){   // N==128; row spread over lanes r, r+16, r+32, r+48
    float s = 0.f;
#pragma unroll
    for (int f = 0; f < 8; f++) s += vv[f][0]+vv[f][1]+vv[f][2]+vv[f][3];
    s += __shfl_xor(s, 16, 64); s += __shfl_xor(s, 32, 64);
    float mean = s * (1.f/128.f);
    float q = 0.f;
#pragma unroll
    for (int f = 0; f < 8; f++)
#pragma unroll
      for (int e = 0; e < 4; e++){ float d = vv[f][e]-mean; q += d*d; }
    q += __shfl_xor(q, 16, 64); q += __shfl_xor(q, 32, 64);
    float rstd = rsqrtf(q*(1.f/128.f) + 1e-5f);
#pragma unroll
    for (int f = 0; f < 8; f++){
      float4 g4 = *(const float4*)&lng[f*16 + 4*ks];
      float4 b4 = *(const float4*)&lnb[f*16 + 4*ks];
      vv[f][0] = (vv[f][0]-mean)*rstd*g4.x + b4.x;
      vv[f][1] = (vv[f][1]-mean)*rstd*g4.y + b4.y;
      vv[f][2] = (vv[f][2]-mean)*rstd*g4.z + b4.z;
      vv[f][3] = (vv[f][3]-mean)*rstd*g4.w + b4.w;
    }
  }
#pragma unroll
  for (int f = 0; f < 8; f++){
    u16x4 o;
#pragma unroll
    for (int e = 0; e < 4; e++) o[e] = f2b(vv[f][e]);
    *(u16x4*)(C + trow*ldC + f*16 + 4*ks) = o;
  }
}

// ---- fused attention+FFN. Blockdiag(KV) is 8 diagonal 16x16 blocks: only MFMA
// j=f>>1 contributes to acc[f] (others multiply exact zeros) -> 8 MFMAs, fragments
// built per-lane straight from L2-hot kvfin; no LDS stage, 2 fewer barriers.
__global__ __launch_bounds__(256) void k_fattnffn(
    const unsigned short* __restrict__ Q, const unsigned short* __restrict__ X,
    const float* __restrict__ kvfin, const unsigned short* __restrict__ W3,
    const float* __restrict__ b3, const float* __restrict__ g0, const float* __restrict__ b0,
    const unsigned short* __restrict__ W1t, const float* __restrict__ b1,
    const unsigned short* __restrict__ W2t, const float* __restrict__ b2,
    const float* __restrict__ g1, const float* __restrict__ lb1,
    unsigned short* __restrict__ Out, float* __restrict__ OutF){
  __shared__ unsigned short Wl[128*128];   // 32KB staged weights
  __shared__ unsigned short UB[64*136];    // 17KB: V -> x0 -> H (per-half)
  int tid = threadIdx.x;
  size_t tb = (size_t)blockIdx.x*64;
  int g = (int)(tb / HWn);
  const float* kvb = kvfin + g*2176;
  int wid = tid >> 6, lane = tid & 63;
  int r = lane & 15, ks = lane >> 4;
  int tl = wid*16 + r;
  size_t trow = tb + tl;
  int myp = ks >> 1;           // which k-half of a j-window this lane covers
  int dlo = (ks & 1)*8;
  // ---- Q fragments ----
  bf16x8 a4[4];
#pragma unroll
  for (int j = 0; j < 4; j++) a4[j] = *(const bf16x8*)(Q + trow*128 + j*32 + ks*8);
  // ---- num MFMA: 8 sparse-blockdiag MFMAs (bit-exact vs dense 32) ----
  f32x4 acc[8] = {};
#pragma unroll
  for (int f = 0; f < 8; f++){
    bf16x8 wf = {};
    if ((f & 1) == myp){
      const float* src = kvb + f*272 + r*16 + dlo;
      float4 s0 = *(const float4*)src, s1 = *(const float4*)(src + 4);
      ((unsigned short*)&wf)[0] = f2b(s0.x); ((unsigned short*)&wf)[1] = f2b(s0.y);
      ((unsigned short*)&wf)[2] = f2b(s0.z); ((unsigned short*)&wf)[3] = f2b(s0.w);
      ((unsigned short*)&wf)[4] = f2b(s1.x); ((unsigned short*)&wf)[5] = f2b(s1.y);
      ((unsigned short*)&wf)[6] = f2b(s1.z); ((unsigned short*)&wf)[7] = f2b(s1.w);
    }
    acc[f] = __builtin_amdgcn_mfma_f32_16x16x32_bf16(wf, a4[f >> 1], acc[f], 0, 0, 0);
  }
  // ---- den partials (ksums read straight from kvfin) ----
  float part[4];
#pragma unroll
  for (int j = 0; j < 4; j++){
    const float* kss = kvb + (2*j + myp)*272 + 256 + dlo;
    float4 k0 = *(const float4*)kss, k1 = *(const float4*)(kss + 4);
    float ksv[8] = {k0.x, k0.y, k0.z, k0.w, k1.x, k1.y, k1.z, k1.w};
    float pj = 0.f;
#pragma unroll
    for (int e = 0; e < 8; e++)
      pj += b2f(((unsigned short*)&a4[j])[e]) * ksv[e];
    part[j] = pj;
  }
  float full0 = part[0] + __shfl_xor(part[0], 16, 64);
  float full1 = part[1] + __shfl_xor(part[1], 16, 64);
  float full2 = part[2] + __shfl_xor(part[2], 16, 64);
  float full3 = part[3] + __shfl_xor(part[3], 16, 64);
  float oth0 = __shfl_xor(full0, 32, 64);
  float oth1 = __shfl_xor(full1, 32, 64);
  float oth2 = __shfl_xor(full2, 32, 64);
  float oth3 = __shfl_xor(full3, 32, 64);
  // V -> UB (wave-own rows; intra-wave LDS dep, no barrier needed)
#pragma unroll
  for (int f = 0; f < 8; f++){
    float fl, ot;
    if (f < 2){ fl = full0; ot = oth0; } else if (f < 4){ fl = full1; ot = oth1; }
    else if (f < 6){ fl = full2; ot = oth2; } else { fl = full3; ot = oth3; }
    float den = ((f & 1) == myp) ? fl : ot;
    float rc = 1.f / (den + 1e-6f);
    u16x4 o;
#pragma unroll
    for (int e = 0; e < 4; e++) o[e] = f2b(acc[f][e] * rc);
    *(u16x4*)&UB[tl*136 + f*16 + 4*ks] = o;
  }
  // ---- stage W3 (first Wl use this kernel; no prior barrier required) ----
#pragma unroll
  for (int i = 0; i < 8; i++){
    int idx = i*256 + tid;
    int row = idx >> 4, c8 = idx & 15;
    int c8s = c8 ^ (row & 7);
    *(bf16x8*)&Wl[row*128 + c8s*8] = *(const bf16x8*)(W3 + (size_t)row*128 + c8*8);
  }
  __syncthreads();
  // ---- out-proj MFMA + residual + LN0 -> x0 (regs + UB) ----
  f32x4 acc2[8] = {};
#pragma unroll
  for (int j = 0; j < 4; j++){
    bf16x8 a = *(const bf16x8*)&UB[tl*136 + j*32 + ks*8];
#pragma unroll
    for (int f = 0; f < 8; f++){
      int row = f*16 + r;
      int c8s = (j*4 + ks) ^ (row & 7);
      bf16x8 w = *(const bf16x8*)&Wl[row*128 + c8s*8];
      acc2[f] = __builtin_amdgcn_mfma_f32_16x16x32_bf16(w, a, acc2[f], 0, 0, 0);
    }
  }
  float vv[8][4];
#pragma unroll
  for (int f = 0; f < 8; f++){
    float4 bi4 = *(const float4*)&b3[f*16 + 4*ks];
    u16x4 rr = *(const u16x4*)(X + trow*128 + f*16 + 4*ks);
    vv[f][0] = acc2[f][0] + bi4.x + b2f(rr[0]);
    vv[f][1] = acc2[f][1] + bi4.y + b2f(rr[1]);
    vv[f][2] = acc2[f][2] + bi4.z + b2f(rr[2]);
    vv[f][3] = acc2[f][3] + bi4.w + b2f(rr[3]);
  }
  {
    float s = 0.f;
#pragma unroll
    for (int f = 0; f < 8; f++) s += vv[f][0]+vv[f][1]+vv[f][2]+vv[f][3];
    s += __shfl_xor(s, 16, 64); s += __shfl_xor(s, 32, 64);
    float mean = s * (1.f/128.f);
    float q = 0.f;
#pragma unroll
    for (int f = 0; f < 8; f++)
#pragma unroll
      for (int e = 0; e < 4; e++){ float d = vv[f][e]-mean; q += d*d; }
    q += __shfl_xor(q, 16, 64); q += __shfl_xor(q, 32, 64);
    float rstd = rsqrtf(q*(1.f/128.f) + 1e-5f);
#pragma unroll
    for (int f = 0; f < 8; f++){
      float4 g4 = *(const float4*)&g0[f*16 + 4*ks];
      float4 b4 = *(const float4*)&b0[f*16 + 4*ks];
      vv[f][0] = (vv[f][0]-mean)*rstd*g4.x + b4.x;
      vv[f][1] = (vv[f][1]-mean)*rstd*g4.y + b4.y;
      vv[f][2] = (vv[f][2]-mean)*rstd*g4.z + b4.z;
      vv[f][3] = (vv[f][3]-mean)*rstd*g4.w + b4.w;
    }
  }
  u16x4 xr[8];                 // x0 kept in regs for FFN2 residual
#pragma unroll
  for (int f = 0; f < 8; f++){
#pragma unroll
    for (int e = 0; e < 4; e++) xr[f][e] = f2b(vv[f][e]);
    *(u16x4*)&UB[tl*136 + f*16 + 4*ks] = xr[f];
  }
  __syncthreads();             // all x0 writes done; W3 readers done
  // ---- load FFN input fragments (x0) into regs; UB may then hold H ----
  bf16x8 areg[4];
#pragma unroll
  for (int j = 0; j < 4; j++) areg[j] = *(const bf16x8*)&UB[tl*136 + j*32 + ks*8];
  // ---- interleaved FFN: for each half: W1h->H, W2k·H accumulate ----
  f32x4 acc3[8] = {};
#pragma unroll
  for (int hh = 0; hh < 2; hh++){
    if (hh > 0) __syncthreads();           // previous Wl readers (W2k0 MFMA) done
    // stage W1 half hh
#pragma unroll
    for (int i = 0; i < 8; i++){
      int idx = i*256 + tid;
      int row = idx >> 4, c8 = idx & 15;
      *(bf16x8*)&Wl[row*128 + (c8 ^ (row & 7))*8] =
          *(const bf16x8*)(W1t + (size_t)(hh*128 + row)*128 + c8*8);
    }
    __syncthreads();
    f32x4 accf[8] = {};
#pragma unroll
    for (int j = 0; j < 4; j++){
#pragma unroll
      for (int f = 0; f < 8; f++){
        int row = f*16 + r;
        int c8s = (j*4 + ks) ^ (row & 7);
        bf16x8 w = *(const bf16x8*)&Wl[row*128 + c8s*8];
        accf[f] = __builtin_amdgcn_mfma_f32_16x16x32_bf16(w, areg[j], accf[f], 0, 0, 0);
      }
    }
#pragma unroll
    for (int f = 0; f < 8; f++){
      float4 bi4 = *(const float4*)&b1[hh*128 + f*16 + 4*ks];
      u16x4 o;
      o[0] = f2b(fmaxf(accf[f][0] + bi4.x, 0.f));
      o[1] = f2b(fmaxf(accf[f][1] + bi4.y, 0.f));
      o[2] = f2b(fmaxf(accf[f][2] + bi4.z, 0.f));
      o[3] = f2b(fmaxf(accf[f][3] + bi4.w, 0.f));
      *(u16x4*)&UB[tl*136 + f*16 + 4*ks] = o;    // H half (own rows)
    }
    __syncthreads();                       // W1 readers done before W2 staging
    // stage W2 k-half hh
#pragma unroll
    for (int i = 0; i < 8; i++){
      int idx = i*256 + tid;
      int row = idx >> 4, c8 = idx & 15;
      *(bf16x8*)&Wl[row*128 + (c8 ^ (row & 7))*8] =
          *(const bf16x8*)(W2t + (size_t)row*256 + hh*128 + c8*8);
    }
    __syncthreads();
#pragma unroll
    for (int j = 0; j < 4; j++){
      bf16x8 a = *(const bf16x8*)&UB[tl*136 + j*32 + ks*8];
#pragma unroll
      for (int f = 0; f < 8; f++){
        int row = f*16 + r;
        int c8s = (j*4 + ks) ^ (row & 7);
        bf16x8 w = *(const bf16x8*)&Wl[row*128 + c8s*8];
        acc3[f] = __builtin_amdgcn_mfma_f32_16x16x32_bf16(w, a, acc3[f], 0, 0, 0);
      }
    }
  }
  // ---- epilogue: + b2 + residual(x0 regs) + LN1 -> Out / OutF ----
#pragma unroll
  for (int f = 0; f < 8; f++){
    float4 bi4 = *(const float4*)&b2[f*16 + 4*ks];
    vv[f][0] = acc3[f][0] + bi4.x + b2f(xr[f][0]);
    vv[f][1] = acc3[f][1] + bi4.y + b2f(xr[f][1]);
    vv[f][2] = acc3[f][2] + bi4.z + b2f(xr[f][2]);
    vv[f][3] = acc3[f][3] + bi4.w + b2f(xr[f][3]);
  }
  float s = 0.f;
#pragma unroll
  for (int f = 0; f < 8; f++) s += vv[f][0]+vv[f][1]+vv[f][2]+vv[f][3];
  s += __shfl_xor(s, 16, 64); s += __shfl_xor(s, 32, 64);
  float mean = s * (1.f/128.f);
  float q = 0.f;
#pragma unroll
  for (int f = 0; f < 8; f++)
#pragma unroll
    for (int e = 0; e < 4; e++){ float d = vv[f][e]-mean; q += d*d; }
  q += __shfl_xor(q, 16, 64); q += __shfl_xor(q, 32, 64);
  float rstd = rsqrtf(q*(1.f/128.f) + 1e-5f);
#pragma unroll
  for (int f = 0; f < 8; f++){
    float4 g4 = *(const float4*)&g1[f*16 + 4*ks];
    float4 b4 = *(const float4*)&lb1[f*16 + 4*ks];
    float o0 = (vv[f][0]-mean)*rstd*g4.x + b4.x;
    float o1 = (vv[f][1]-mean)*rstd*g4.y + b4.y;
    float o2 = (vv[f][2]-mean)*rstd*g4.z + b4.z;
    float o3 = (vv[f][3]-mean)*rstd*g4.w + b4.w;
    if (Out){
      u16x4 o = { f2b(o0), f2b(o1), f2b(o2), f2b(o3) };
      *(u16x4*)(Out + trow*128 + f*16 + 4*ks) = o;
    }
    if (OutF){
      float4 of = { o0, o1, o2, o3 };
      *(float4*)(OutF + trow*128 + f*16 + 4*ks) = of;
    }
  }
}

// ---------------- KV partial: transposed staging, atomic reduce into KVFIN ----------------
__global__ __launch_bounds__(256) void k_kvpart(const unsigned short* __restrict__ Kb,
                         const unsigned short* __restrict__ Vb, float* __restrict__ fin){
  __shared__ float Ks[16][260], Vs[16][260];
  int bi = blockIdx.x;
  int chunk = bi % 80; int h = (bi / 80) & 7; int g = bi / 640;
  int s0 = chunk * 256;
  int tid = threadIdx.x;
#pragma unroll
  for (int rr = 0; rr < 8; rr++){
    int idx = rr*256 + tid;
    int s = idx >> 3, d2 = idx & 7;
    size_t gg = ((size_t)(g*HWn + s0 + s))*128 + h*16 + d2*2;
    Ks[d2*2  ][s] = b2f(Kb[gg]);
    Ks[d2*2+1][s] = b2f(Kb[gg+1]);
    Vs[d2*2  ][s] = b2f(Vb[gg]);
    Vs[d2*2+1][s] = b2f(Vb[gg+1]);
  }
  __syncthreads();
  int m = tid >> 4, d = tid & 15;
  float acc = 0.f, ksum = 0.f;
#pragma unroll 4
  for (int s4 = 0; s4 < 64; s4++){
    float4 kv = *(const float4*)&Ks[d][s4*4];
    float4 vv = *(const float4*)&Vs[m][s4*4];
    acc  += kv.x*vv.x + kv.y*vv.y + kv.z*vv.z + kv.w*vv.w;
    ksum += kv.x + kv.y + kv.z + kv.w;
  }
  float* fb = fin + (size_t)(g*8 + h)*272;
  atomicAdd(&fb[tid], acc);
  if (m == 0) atomicAdd(&fb[256 + d], ksum);
}

// ---------------- homography warp + bilinear sample (pixel-major ctx, bf16) ----------------
__global__ __launch_bounds__(128) void k_warp(const unsigned short* __restrict__ ctxref,
     const float* __restrict__ depth, const float* __restrict__ projs,
     unsigned short* __restrict__ ctxsrc){
  int bi = blockIdx.x; int n = bi / HWn; int p = bi - n*HWn;
  int y = p / WW, x = p - y*WW;
  const float* pr = &projs[n*12];
  float d = depth[n*HWn + p];
  float fx = (float)x, fy = (float)y;
  float px = (pr[0]*fx + pr[1]*fy + pr[2])*d + pr[9];
  float py = (pr[3]*fx + pr[4]*fy + pr[5])*d + pr[10];
  float pz = (pr[6]*fx + pr[7]*fy + pr[8])*d + pr[11];
  if (pz == 0.f) pz = 1e-9f;
  float xs = px/pz, ys = py/pz;
  float x0 = floorf(xs), y0 = floorf(ys);
  float wx = xs - x0, wy = ys - y0;
  int c = threadIdx.x;
  float acc = 0.f;
#pragma unroll
  for (int dy = 0; dy < 2; dy++){
    float cy = y0 + dy;
    float wyv = dy ? wy : 1.f - wy;
#pragma unroll
    for (int dx = 0; dx < 2; dx++){
      float cx = x0 + dx;
      float wxv = dx ? wx : 1.f - wx;
      bool valid = (cx >= 0.f) && (cx <= (float)(WW-1)) && (cy >= 0.f) && (cy <= (float)(HH-1));
      int xi = (int)fminf(fmaxf(cx, 0.f), (float)(WW-1));
      int yi = (int)fminf(fmaxf(cy, 0.f), (float)(HH-1));
      float v = b2f(ctxref[((size_t)(n*HWn) + yi*WW + xi)*128 + c]);
      acc += valid ? wxv*wyv*v : 0.f;
    }
  }
  ctxsrc[(size_t)bi*128 + c] = f2b(acc);
}

// ---------------- token build (both streams in one dispatch, z selects) ----------------
__global__ __launch_bounds__(256) void k_build2(const float* __restrict__ featR,
      const float* __restrict__ featS,
      const unsigned short* __restrict__ ctxR, const unsigned short* __restrict__ ctxS,
      unsigned short* __restrict__ outR, unsigned short* __restrict__ outS){
  __shared__ float tile[32][33];
  int tx = threadIdx.x, ty = threadIdx.y;
  int z = blockIdx.z; int b = z & (BN-1); int sel = z >> 1;
  const float* feat = sel ? featS : featR;
  const unsigned short* ctx = sel ? ctxS : ctxR;
  unsigned short* out = sel ? outS : outR;
  int p0 = blockIdx.x*32, c0 = blockIdx.y*32;
  for (int i = ty; i < 32; i += 8)
    tile[i][tx] = feat[((size_t)(b*CD + c0 + i))*HWn + p0 + tx];
  __syncthreads();
  const float LOG1E4_32 = 0.28782313662425572f;  // ln(10000)/32
  for (int r = ty; r < 32; r += 8){
    int p = p0 + r, c = c0 + tx;
    int y = p / WW, x = p - y*WW;
    int i = c >> 2, j = c & 3;
    float dv = __expf(-(float)i * LOG1E4_32);
    float pos = (j < 2) ? (float)(x + 1) : (float)(y + 1);
    float arg = pos * dv;
    float pe = (j & 1) ? cosf(arg) : sinf(arg);
    size_t o = ((size_t)(b*HWn) + p)*128 + c;
    out[o] = f2b(tile[tx][r] + pe + b2f(ctx[o]));
  }
}

// ---------------- host ----------------
extern "C" void kernel_launch(void* const* d_in, const int* in_sizes, int n_in,
                              void* d_out, int out_size, void* d_ws, size_t ws_size,
                              hipStream_t stream) {
  const float* ref_feature = (const float*)d_in[0];
  const float* src_feature = (const float*)d_in[1];
  const float* ref_proj    = (const float*)d_in[2];
  const float* ref_i2w     = (const float*)d_in[4];
  const float* src_i2w     = (const float*)d_in[5];
  const float* depth       = (const float*)d_in[6];
  const float* attn_w      = (const float*)d_in[7];
  const float* attn_b      = (const float*)d_in[8];
  const float* ffn_w1      = (const float*)d_in[9];
  const float* ffn_b1      = (const float*)d_in[10];
  const float* ffn_w2      = (const float*)d_in[11];
  const float* ffn_b2      = (const float*)d_in[12];
  const float* ln_g        = (const float*)d_in[13];
  const float* ln_b        = (const float*)d_in[14];
  const float* rc_w        = (const float*)d_in[15];
  const float* rc_b        = (const float*)d_in[16];
  const float* bn2_g       = (const float*)d_in[17];
  const float* bn2_b       = (const float*)d_in[18];
  const float* cc_w        = (const float*)d_in[19];
  const float* cc_b        = (const float*)d_in[20];
  const float* bn1_g       = (const float*)d_in[21];
  const float* bn1_b       = (const float*)d_in[22];
  const float* fc1_w       = (const float*)d_in[23];
  const float* fc1_b       = (const float*)d_in[24];
  const float* fc2_w       = (const float*)d_in[25];
  const float* fc2_b       = (const float*)d_in[26];
  const float* ser_w       = (const float*)d_in[27];
  const float* ser_b       = (const float*)d_in[28];
  const float* see_w       = (const float*)d_in[29];
  const float* see_b       = (const float*)d_in[30];

  const size_t small_f32 = (size_t)4*2176 + 32 + 256;
  const size_t small_bytes = small_f32*4 + (size_t)540672*2 + 4096;
  const size_t need_batch = (size_t)TOKN*2*8 + small_bytes;   // streams(2)+QKV(6) bf16
  bool BATCH = ws_size >= need_batch;
  const size_t CSEG = BATCH ? 2*TOKN : TOKN;

  char* p = (char*)d_ws;
  unsigned short* Rm = (unsigned short*)p; p += TOKN*2;
  unsigned short* Sm = (unsigned short*)p; p += TOKN*2;      // contiguous after Rm
  unsigned short* QB = (unsigned short*)p; p += CSEG*3*2;
  unsigned short* KB = QB + CSEG;
  unsigned short* VB = QB + 2*CSEG;
  float* KVFIN  = (float*)p; p += (size_t)(BATCH?4:2)*2176*4;
  float* PROJ   = (float*)p; p += 32*4;
  float* GATE   = (float*)p; p += 256*4;
  unsigned short* WT = (unsigned short*)p;

  float* OUT = (float*)d_out;

  k_wconv<<<2113, 256, 0, stream>>>(attn_w, ffn_w1, ffn_w2, cc_w, WT,
      ref_proj, src_i2w, ref_i2w, bn1_g, bn1_b, fc1_w, fc1_b,
      fc2_w, fc2_b, ser_w, ser_b, see_w, see_b, PROJ, GATE);
  k_hmap<<<TT, 128, 0, stream>>>(depth, rc_w, rc_b, bn2_g, bn2_b, GATE, QB);
  k_bgemm6<128,0,0><<<dim3(TT/64, 1), 256, 0, stream>>>(
      QB, QB, 128, WT + 524288, cc_b, 0, nullptr, KB, 0, 128, nullptr, nullptr,
      nullptr, 0);
  k_warp<<<TT, 128, 0, stream>>>(KB, depth, PROJ, VB);
  k_build2<<<dim3(HWn/32, 4, 2*BN), dim3(32, 8), 0, stream>>>(
      ref_feature, src_feature, KB, VB, Rm, Sm);

  auto encode = [&](unsigned short* x, const unsigned short* srcp, int l, int nTok,
                    unsigned short* outBf, float* outF){
    const unsigned short* ATW = WT + (size_t)l*65536;          // [4][128][128]
    const unsigned short* F1T = WT + 262144 + (size_t)l*32768; // [256][128]
    const unsigned short* F2T = WT + 393216 + (size_t)l*32768; // [128][256]
    const float* Bv = attn_b + (size_t)l*512;
    const float* g0 = ln_g + (size_t)l*256; const float* b0 = ln_b + (size_t)l*256;
    int nb = nTok/64, ng = nTok/HWn;
    // QKV in one dispatch: sec0 reads x, secs 1-2 read srcp; block(0,0) zeroes KVFIN
    k_bgemm6<128,2,0><<<dim3(nb, 3), 256, 0, stream>>>(x, srcp, 128, ATW, Bv, 0b011,
                                              nullptr, QB, CSEG, 128, nullptr, nullptr,
                                              KVFIN, ng*2176);
    // KV partials atomically accumulated straight into KVFIN (no reduce dispatch)
    k_kvpart<<<ng*640, 256, 0, stream>>>(KB, VB, KVFIN);
    // fused attn + FFN: out <- LN1(x0 + FFN(x0)), x0 = LN0(x + attn)
    k_fattnffn<<<nb, 256, 0, stream>>>(QB, x, KVFIN, ATW + 3*16384, Bv + 384, g0, b0,
                                       F1T, ffn_b1 + (size_t)l*256, F2T,
                                       ffn_b2 + (size_t)l*128, g0 + 128, b0 + 128,
                                       outBf, outF);
  };

  // layer 0: self
  if (BATCH) encode(Rm, Rm, 0, 2*TT, Rm, nullptr);
  else { encode(Rm, Rm, 0, TT, Rm, nullptr); encode(Sm, Sm, 0, TT, Sm, nullptr); }
  // layer 1: cross (src uses updated ref)
  encode(Rm, Sm, 1, TT, Rm, nullptr); encode(Sm, Rm, 1, TT, Sm, nullptr);
  // layer 2: self
  if (BATCH) encode(Rm, Rm, 2, 2*TT, Rm, nullptr);
  else { encode(Rm, Rm, 2, TT, Rm, nullptr); encode(Sm, Sm, 2, TT, Sm, nullptr); }
  // layer 3: cross — final outputs fused to f32 OUT (no k_tofp32 dispatch)
  encode(Rm, Sm, 3, TT, Rm, OUT);              // Rm still read by next encode's K/V
  encode(Sm, Rm, 3, TT, nullptr, OUT + TOKN);  // Sm unused afterwards: f32 only
}

// Round 35
// 551.356 us; speedup vs baseline: 1.0305x; 1.0305x over previous
//
#include <hip/hip_runtime.h>
#include <math.h>

#define BN 2
#define HH 128
#define WW 160
#define HWn (HH*WW)          // 20480
#define CD 128
#define TT (BN*HWn)          // 40960 tokens per stream
#define TOKN ((size_t)TT*CD) // 5,242,880 elements

typedef __attribute__((ext_vector_type(8))) short bf16x8;
typedef __attribute__((ext_vector_type(4))) float f32x4;
typedef __attribute__((ext_vector_type(4))) unsigned short u16x4;

__device__ __forceinline__ float b2f(unsigned short s){
  unsigned u = ((unsigned)s) << 16;
  return __builtin_bit_cast(float, u);
}
__device__ __forceinline__ unsigned short f2b(float f){
  unsigned u = __builtin_bit_cast(unsigned, f);
  u = (u + 0x7fffu + ((u >> 16) & 1u)) >> 16;   // RNE
  return (unsigned short)u;
}

// ---------------- weight convert + (block 2112) tiny precompute ----------------
__global__ __launch_bounds__(256) void k_wconv(const float* __restrict__ attn_w,
      const float* __restrict__ ffn_w1, const float* __restrict__ ffn_w2,
      const float* __restrict__ cc_w, unsigned short* __restrict__ wt,
      const float* __restrict__ ref_proj, const float* __restrict__ src_i2w,
      const float* __restrict__ cam16,
      const float* __restrict__ bn1_g, const float* __restrict__ bn1_b,
      const float* __restrict__ fc1_w, const float* __restrict__ fc1_b,
      const float* __restrict__ fc2_w, const float* __restrict__ fc2_b,
      const float* __restrict__ ser_w, const float* __restrict__ ser_b,
      const float* __restrict__ see_w, const float* __restrict__ see_b,
      float* __restrict__ projsmall, float* __restrict__ gate){
  if (blockIdx.x == 2112){    // ---- small precompute: proj mats + SE gate ----
    __shared__ float mi[BN][16], t1[BN][128], t2[BN][128];
    int tid = threadIdx.x;
    const float inv_std = rsqrtf(1.0f + 1e-5f);
    if (tid < 32){
      int b = tid >> 4, idx = tid & 15, i = idx >> 2, k = idx & 3;
      float acc = 0.f;
      for (int j = 0; j < 4; j++) acc += ref_proj[b*16 + i*4 + j] * src_i2w[b*16 + j*4 + k];
      if (i < 3 && k < 3) projsmall[b*12 + i*3 + k] = acc;
      if (i < 3 && k == 3) projsmall[b*12 + 9 + i] = acc;
      mi[b][idx] = cam16[b*16 + idx] * inv_std * bn1_g[idx] + bn1_b[idx];
    }
    __syncthreads();
    int b = tid >> 7, c = tid & 127;
    float a = 0.f;
    for (int j = 0; j < 16; j++) a += mi[b][j] * fc1_w[j*128 + c];
    t1[b][c] = fmaxf(a + fc1_b[c], 0.f);
    __syncthreads();
    a = 0.f;
    for (int k = 0; k < 128; k++) a += t1[b][k] * fc2_w[k*128 + c];
    t2[b][c] = a + fc2_b[c];
    __syncthreads();
    a = 0.f;
    for (int k = 0; k < 128; k++) a += t2[b][k] * ser_w[k*128 + c];
    t1[b][c] = fmaxf(a + ser_b[c], 0.f);
    __syncthreads();
    a = 0.f;
    for (int k = 0; k < 128; k++) a += t1[b][k] * see_w[k*128 + c];
    a += see_b[c];
    gate[b*128 + c] = 1.f / (1.f + __expf(-a));
    return;
  }
  int i = blockIdx.x*256 + threadIdx.x;
  float v;
  if (i < 262144){                       // attn: [(l*4+m)][n][k] <- attn_w[lm][k][n]
    int k = i & 127, n = (i >> 7) & 127, lm = i >> 14;
    v = attn_w[((size_t)lm*128 + k)*128 + n];
  } else if (i < 393216){ int j = i - 262144;   // f1t: [l][n<256][k<128]
    int k = j & 127, n = (j >> 7) & 255, l = j >> 15;
    v = ffn_w1[((size_t)l*128 + k)*256 + n];
  } else if (i < 524288){ int j = i - 393216;   // f2t: [l][n<128][k<256]
    int k = j & 255, n = (j >> 8) & 127, l = j >> 15;
    v = ffn_w2[((size_t)l*256 + k)*128 + n];
  } else if (i < 540672){ int j = i - 524288;   // cct: [o][c] <- cc_w[c][o]
    int k = j & 127, n = j >> 7;
    v = cc_w[(size_t)k*128 + n];
  } else return;
  wt[i] = f2b(v);
}

// ---------------- K1: conv3x3(depth) + bn + relu + gate, pixel-major, bf16 out ----------------
__global__ __launch_bounds__(128) void k_hmap(const float* __restrict__ depth,
                       const float* __restrict__ rc_w, const float* __restrict__ rc_b,
                       const float* __restrict__ bn2_g, const float* __restrict__ bn2_b,
                       const float* __restrict__ gate, unsigned short* __restrict__ G){
  int bi = blockIdx.x; int n = bi / HWn; int p = bi - n*HWn;
  int y = p / WW, x = p - y*WW;
  int c = threadIdx.x;
  const float inv_std = rsqrtf(1.f + 1e-5f);
  float acc = 0.f;
#pragma unroll
  for (int ky = 0; ky < 3; ky++){
    int yy = y + ky - 1;
#pragma unroll
    for (int kx = 0; kx < 3; kx++){
      int xx = x + kx - 1;
      float v = (yy >= 0 && yy < HH && xx >= 0 && xx < WW) ? depth[n*HWn + yy*WW + xx] : 0.f;
      acc += v * rc_w[c*9 + ky*3 + kx];
    }
  }
  acc += rc_b[c];
  acc = fmaxf(acc * inv_std * bn2_g[c] + bn2_b[c], 0.f);
  G[(size_t)bi*128 + c] = f2b(acc * gate[n*128 + c]);
}

// ---- bf16 MFMA GEMM: 64 tokens/block (4 waves x 16), W staged in XOR-swizzled
// LDS in 128-col halves. acc[8] per wave. Section sec>0 reads A2 (cross QKV).
// Block (0,0) additionally zero-fills zfin[0..zn) (KVFIN for the next dispatch).
template<int K, int ACT, int LN>  // ACT: 1 relu, 2 elu+1 (where amask bit set)
__global__ __launch_bounds__(256) void k_bgemm6(
    const unsigned short* __restrict__ A, const unsigned short* __restrict__ A2, int ldA,
    const unsigned short* __restrict__ Wt,
    const float* __restrict__ bias, int amask,
    const unsigned short* __restrict__ resid,
    unsigned short* __restrict__ Cbase, size_t secStride, int ldC,
    const float* __restrict__ lng, const float* __restrict__ lnb,
    float* zfin, int zn){
  __shared__ unsigned short Wl[128*128];   // one 128-col half at a time, swizzled
  constexpr int NH = K/128;
  int tid = threadIdx.x;
  int wid = tid >> 6, lane = tid & 63;
  int sec = blockIdx.y;
  if (zfin && blockIdx.x == 0 && sec == 0){
    for (int i = tid; i < zn; i += 256) zfin[i] = 0.f;
  }
  const unsigned short* Ab = (sec == 0) ? A : A2;
  const unsigned short* Ws = Wt + (size_t)sec*128*K;
  const float* bs = bias + sec*128;
  unsigned short* C = Cbase + (size_t)sec*secStride;
  int r = lane & 15, ks = lane >> 4;
  size_t t0 = (size_t)blockIdx.x*64 + wid*16;
  const unsigned short* ap = Ab + (t0 + r)*ldA + ks*8;
  f32x4 acc[8] = {};
#pragma unroll
  for (int hh = 0; hh < NH; hh++){
    if (hh > 0) __syncthreads();
    // stage 128x128 half, swizzle c8 -> c8 ^ (row&7)
#pragma unroll
    for (int i = 0; i < 8; i++){
      int idx = i*256 + tid;
      int row = idx >> 4, c8 = idx & 15;
      int c8s = c8 ^ (row & 7);
      *(bf16x8*)&Wl[row*128 + c8s*8] = *(const bf16x8*)(Ws + (size_t)row*K + hh*128 + c8*8);
    }
    __syncthreads();
#pragma unroll
    for (int j = 0; j < 4; j++){
      bf16x8 a = *(const bf16x8*)(ap + hh*128 + j*32);
#pragma unroll
      for (int f = 0; f < 8; f++){
        int row = f*16 + r;
        int c8s = (j*4 + ks) ^ (row & 7);
        bf16x8 w = *(const bf16x8*)&Wl[row*128 + c8s*8];
        acc[f] = __builtin_amdgcn_mfma_f32_16x16x32_bf16(w, a, acc[f], 0, 0, 0);
      }
    }
  }
  bool act = (amask >> sec) & 1;
  size_t trow = t0 + r;
  float vv[8][4];
#pragma unroll
  for (int f = 0; f < 8; f++){
    float4 bi4 = *(const float4*)&bs[f*16 + 4*ks];
    vv[f][0] = acc[f][0] + bi4.x; vv[f][1] = acc[f][1] + bi4.y;
    vv[f][2] = acc[f][2] + bi4.z; vv[f][3] = acc[f][3] + bi4.w;
    if (resid){
      u16x4 rr = *(const u16x4*)(resid + trow*128 + f*16 + 4*ks);
#pragma unroll
      for (int e = 0; e < 4; e++) vv[f][e] += b2f(rr[e]);
    }
    if (act){
#pragma unroll
      for (int e = 0; e < 4; e++){
        float x = vv[f][e];
        if (ACT == 1) x = fmaxf(x, 0.f);
        if (ACT == 2) x = x > 0.f ? x + 1.f : __expf(x);
        vv[f][e] = x;
      }
    }
  }
  if (LN){   // N==128; row spread over lanes r, r+16, r+32, r+48
    float s = 0.f;
#pragma unroll
    for (int f = 0; f < 8; f++) s += vv[f][0]+vv[f][1]+vv[f][2]+vv[f][3];
    s += __shfl_xor(s, 16, 64); s += __shfl_xor(s, 32, 64);
    float mean = s * (1.f/128.f);
    float q = 0.f;
#pragma unroll
    for (int f = 0; f < 8; f++)
#pragma unroll
      for (int e = 0; e < 4; e++){ float d = vv[f][e]-mean; q += d*d; }
    q += __shfl_xor(q, 16, 64); q += __shfl_xor(q, 32, 64);
    float rstd = rsqrtf(q*(1.f/128.f) + 1e-5f);
#pragma unroll
    for (int f = 0; f < 8; f++){
      float4 g4 = *(const float4*)&lng[f*16 + 4*ks];
      float4 b4 = *(const float4*)&lnb[f*16 + 4*ks];
      vv[f][0] = (vv[f][0]-mean)*rstd*g4.x + b4.x;
      vv[f][1] = (vv[f][1]-mean)*rstd*g4.y + b4.y;
      vv[f][2] = (vv[f][2]-mean)*rstd*g4.z + b4.z;
      vv[f][3] = (vv[f][3]-mean)*rstd*g4.w + b4.w;
    }
  }
#pragma unroll
  for (int f = 0; f < 8; f++){
    u16x4 o;
#pragma unroll
    for (int e = 0; e < 4; e++) o[e] = f2b(vv[f][e]);
    *(u16x4*)(C + trow*ldC + f*16 + 4*ks) = o;
  }
}

// ---- fused attention+FFN: LN0(X + linattn(Q)@W3 + b3) -> x0; LN1(x0 + FFN(x0)) -> Out
// Out (bf16) nullable; OutF (f32, final-layer fused output) nullable.
__global__ __launch_bounds__(256) void k_fattnffn(
    const unsigned short* __restrict__ Q, const unsigned short* __restrict__ X,
    const float* __restrict__ kvfin, const unsigned short* __restrict__ W3,
    const float* __restrict__ b3, const float* __restrict__ g0, const float* __restrict__ b0,
    const unsigned short* __restrict__ W1t, const float* __restrict__ b1,
    const unsigned short* __restrict__ W2t, const float* __restrict__ b2,
    const float* __restrict__ g1, const float* __restrict__ lb1,
    unsigned short* __restrict__ Out, float* __restrict__ OutF){
  __shared__ unsigned short Wl[128*128];   // 32KB staged weights
  __shared__ unsigned short UB[64*136];    // 17KB: V -> x0 -> H (per-half)
  __shared__ float ksums[8][16];
  int tid = threadIdx.x;
  size_t tb = (size_t)blockIdx.x*64;
  int g = (int)(tb / HWn);
  const float* kvb = kvfin + g*2176;
  // ---- stage blockdiag(KV) ----
  {
    int row = tid >> 1, half = tid & 1;
    int h = row >> 4, m = row & 15;
    int swz = row & 7;
#pragma unroll
    for (int c8i = 0; c8i < 8; c8i++){
      int c8 = half*8 + c8i;
      bf16x8 val = {};
      if ((c8 >> 1) == h){
        int d0 = (c8 & 1)*8;
        const float* src = kvb + h*272 + m*16 + d0;
#pragma unroll
        for (int e = 0; e < 8; e++) ((unsigned short*)&val)[e] = f2b(src[e]);
      }
      *(bf16x8*)&Wl[row*128 + (c8 ^ swz)*8] = val;
    }
  }
  if (tid < 128) ksums[tid >> 4][tid & 15] = kvb[(tid >> 4)*272 + 256 + (tid & 15)];
  __syncthreads();
  int wid = tid >> 6, lane = tid & 63;
  int r = lane & 15, ks = lane >> 4;
  int tl = wid*16 + r;
  size_t trow = tb + tl;
  // ---- num MFMA + den partials ----
  f32x4 acc[8] = {};
  float part0 = 0.f, part1 = 0.f, part2 = 0.f, part3 = 0.f;
  int myp = ks >> 1;
  int dlo = (ks & 1)*8;
#pragma unroll
  for (int j = 0; j < 4; j++){
    bf16x8 a = *(const bf16x8*)(Q + trow*128 + j*32 + ks*8);
    float pj = 0.f;
    int hj = 2*j + myp;
#pragma unroll
    for (int e = 0; e < 8; e++)
      pj += b2f(((unsigned short*)&a)[e]) * ksums[hj][dlo + e];
    if (j == 0) part0 = pj; else if (j == 1) part1 = pj;
    else if (j == 2) part2 = pj; else part3 = pj;
#pragma unroll
    for (int f = 0; f < 8; f++){
      int row = f*16 + r;
      int c8s = (j*4 + ks) ^ (row & 7);
      bf16x8 w = *(const bf16x8*)&Wl[row*128 + c8s*8];
      acc[f] = __builtin_amdgcn_mfma_f32_16x16x32_bf16(w, a, acc[f], 0, 0, 0);
    }
  }
  float full0 = part0 + __shfl_xor(part0, 16, 64);
  float full1 = part1 + __shfl_xor(part1, 16, 64);
  float full2 = part2 + __shfl_xor(part2, 16, 64);
  float full3 = part3 + __shfl_xor(part3, 16, 64);
  float oth0 = __shfl_xor(full0, 32, 64);
  float oth1 = __shfl_xor(full1, 32, 64);
  float oth2 = __shfl_xor(full2, 32, 64);
  float oth3 = __shfl_xor(full3, 32, 64);
  // V -> UB
#pragma unroll
  for (int f = 0; f < 8; f++){
    float fl, ot;
    if (f < 2){ fl = full0; ot = oth0; } else if (f < 4){ fl = full1; ot = oth1; }
    else if (f < 6){ fl = full2; ot = oth2; } else { fl = full3; ot = oth3; }
    float den = ((f & 1) == myp) ? fl : ot;
    float rc = 1.f / (den + 1e-6f);
    u16x4 o;
#pragma unroll
    for (int e = 0; e < 4; e++) o[e] = f2b(acc[f][e] * rc);
    *(u16x4*)&UB[tl*136 + f*16 + 4*ks] = o;
  }
  __syncthreads();
  // ---- stage W3 ----
#pragma unroll
  for (int i = 0; i < 8; i++){
    int idx = i*256 + tid;
    int row = idx >> 4, c8 = idx & 15;
    int c8s = c8 ^ (row & 7);
    *(bf16x8*)&Wl[row*128 + c8s*8] = *(const bf16x8*)(W3 + (size_t)row*128 + c8*8);
  }
  __syncthreads();
  // ---- out-proj MFMA + residual + LN0 -> x0 (regs + UB) ----
  f32x4 acc2[8] = {};
#pragma unroll
  for (int j = 0; j < 4; j++){
    bf16x8 a = *(const bf16x8*)&UB[tl*136 + j*32 + ks*8];
#pragma unroll
    for (int f = 0; f < 8; f++){
      int row = f*16 + r;
      int c8s = (j*4 + ks) ^ (row & 7);
      bf16x8 w = *(const bf16x8*)&Wl[row*128 + c8s*8];
      acc2[f] = __builtin_amdgcn_mfma_f32_16x16x32_bf16(w, a, acc2[f], 0, 0, 0);
    }
  }
  float vv[8][4];
#pragma unroll
  for (int f = 0; f < 8; f++){
    float4 bi4 = *(const float4*)&b3[f*16 + 4*ks];
    u16x4 rr = *(const u16x4*)(X + trow*128 + f*16 + 4*ks);
    vv[f][0] = acc2[f][0] + bi4.x + b2f(rr[0]);
    vv[f][1] = acc2[f][1] + bi4.y + b2f(rr[1]);
    vv[f][2] = acc2[f][2] + bi4.z + b2f(rr[2]);
    vv[f][3] = acc2[f][3] + bi4.w + b2f(rr[3]);
  }
  {
    float s = 0.f;
#pragma unroll
    for (int f = 0; f < 8; f++) s += vv[f][0]+vv[f][1]+vv[f][2]+vv[f][3];
    s += __shfl_xor(s, 16, 64); s += __shfl_xor(s, 32, 64);
    float mean = s * (1.f/128.f);
    float q = 0.f;
#pragma unroll
    for (int f = 0; f < 8; f++)
#pragma unroll
      for (int e = 0; e < 4; e++){ float d = vv[f][e]-mean; q += d*d; }
    q += __shfl_xor(q, 16, 64); q += __shfl_xor(q, 32, 64);
    float rstd = rsqrtf(q*(1.f/128.f) + 1e-5f);
#pragma unroll
    for (int f = 0; f < 8; f++){
      float4 g4 = *(const float4*)&g0[f*16 + 4*ks];
      float4 b4 = *(const float4*)&b0[f*16 + 4*ks];
      vv[f][0] = (vv[f][0]-mean)*rstd*g4.x + b4.x;
      vv[f][1] = (vv[f][1]-mean)*rstd*g4.y + b4.y;
      vv[f][2] = (vv[f][2]-mean)*rstd*g4.z + b4.z;
      vv[f][3] = (vv[f][3]-mean)*rstd*g4.w + b4.w;
    }
  }
  u16x4 xr[8];                 // x0 kept in regs for FFN2 residual
#pragma unroll
  for (int f = 0; f < 8; f++){
#pragma unroll
    for (int e = 0; e < 4; e++) xr[f][e] = f2b(vv[f][e]);
    *(u16x4*)&UB[tl*136 + f*16 + 4*ks] = xr[f];
  }
  __syncthreads();             // all x0 writes done; W3 readers done
  // ---- load FFN input fragments (x0) into regs; UB may then hold H ----
  bf16x8 areg[4];
#pragma unroll
  for (int j = 0; j < 4; j++) areg[j] = *(const bf16x8*)&UB[tl*136 + j*32 + ks*8];
  // ---- interleaved FFN: for each half: W1h->H, W2k·H accumulate ----
  f32x4 acc3[8] = {};
#pragma unroll
  for (int hh = 0; hh < 2; hh++){
    if (hh > 0) __syncthreads();           // previous Wl readers (W2k0 MFMA) done
    // stage W1 half hh
#pragma unroll
    for (int i = 0; i < 8; i++){
      int idx = i*256 + tid;
      int row = idx >> 4, c8 = idx & 15;
      *(bf16x8*)&Wl[row*128 + (c8 ^ (row & 7))*8] =
          *(const bf16x8*)(W1t + (size_t)(hh*128 + row)*128 + c8*8);
    }
    __syncthreads();
    f32x4 accf[8] = {};
#pragma unroll
    for (int j = 0; j < 4; j++){
#pragma unroll
      for (int f = 0; f < 8; f++){
        int row = f*16 + r;
        int c8s = (j*4 + ks) ^ (row & 7);
        bf16x8 w = *(const bf16x8*)&Wl[row*128 + c8s*8];
        accf[f] = __builtin_amdgcn_mfma_f32_16x16x32_bf16(w, areg[j], accf[f], 0, 0, 0);
      }
    }
#pragma unroll
    for (int f = 0; f < 8; f++){
      float4 bi4 = *(const float4*)&b1[hh*128 + f*16 + 4*ks];
      u16x4 o;
      o[0] = f2b(fmaxf(accf[f][0] + bi4.x, 0.f));
      o[1] = f2b(fmaxf(accf[f][1] + bi4.y, 0.f));
      o[2] = f2b(fmaxf(accf[f][2] + bi4.z, 0.f));
      o[3] = f2b(fmaxf(accf[f][3] + bi4.w, 0.f));
      *(u16x4*)&UB[tl*136 + f*16 + 4*ks] = o;    // H half (own rows)
    }
    __syncthreads();                       // W1 readers done before W2 staging
    // stage W2 k-half hh
#pragma unroll
    for (int i = 0; i < 8; i++){
      int idx = i*256 + tid;
      int row = idx >> 4, c8 = idx & 15;
      *(bf16x8*)&Wl[row*128 + (c8 ^ (row & 7))*8] =
          *(const bf16x8*)(W2t + (size_t)row*256 + hh*128 + c8*8);
    }
    __syncthreads();
#pragma unroll
    for (int j = 0; j < 4; j++){
      bf16x8 a = *(const bf16x8*)&UB[tl*136 + j*32 + ks*8];
#pragma unroll
      for (int f = 0; f < 8; f++){
        int row = f*16 + r;
        int c8s = (j*4 + ks) ^ (row & 7);
        bf16x8 w = *(const bf16x8*)&Wl[row*128 + c8s*8];
        acc3[f] = __builtin_amdgcn_mfma_f32_16x16x32_bf16(w, a, acc3[f], 0, 0, 0);
      }
    }
  }
  // ---- epilogue: + b2 + residual(x0 regs) + LN1 -> Out / OutF ----
#pragma unroll
  for (int f = 0; f < 8; f++){
    float4 bi4 = *(const float4*)&b2[f*16 + 4*ks];
    vv[f][0] = acc3[f][0] + bi4.x + b2f(xr[f][0]);
    vv[f][1] = acc3[f][1] + bi4.y + b2f(xr[f][1]);
    vv[f][2] = acc3[f][2] + bi4.z + b2f(xr[f][2]);
    vv[f][3] = acc3[f][3] + bi4.w + b2f(xr[f][3]);
  }
  float s = 0.f;
#pragma unroll
  for (int f = 0; f < 8; f++) s += vv[f][0]+vv[f][1]+vv[f][2]+vv[f][3];
  s += __shfl_xor(s, 16, 64); s += __shfl_xor(s, 32, 64);
  float mean = s * (1.f/128.f);
  float q = 0.f;
#pragma unroll
  for (int f = 0; f < 8; f++)
#pragma unroll
    for (int e = 0; e < 4; e++){ float d = vv[f][e]-mean; q += d*d; }
  q += __shfl_xor(q, 16, 64); q += __shfl_xor(q, 32, 64);
  float rstd = rsqrtf(q*(1.f/128.f) + 1e-5f);
#pragma unroll
  for (int f = 0; f < 8; f++){
    float4 g4 = *(const float4*)&g1[f*16 + 4*ks];
    float4 b4 = *(const float4*)&lb1[f*16 + 4*ks];
    float o0 = (vv[f][0]-mean)*rstd*g4.x + b4.x;
    float o1 = (vv[f][1]-mean)*rstd*g4.y + b4.y;
    float o2 = (vv[f][2]-mean)*rstd*g4.z + b4.z;
    float o3 = (vv[f][3]-mean)*rstd*g4.w + b4.w;
    if (Out){
      u16x4 o = { f2b(o0), f2b(o1), f2b(o2), f2b(o3) };
      *(u16x4*)(Out + trow*128 + f*16 + 4*ks) = o;
    }
    if (OutF){
      float4 of = { o0, o1, o2, o3 };
      *(float4*)(OutF + trow*128 + f*16 + 4*ks) = of;
    }
  }
}

// ---------------- KV partial: transposed staging, atomic reduce into KVFIN ----------------
__global__ __launch_bounds__(256) void k_kvpart(const unsigned short* __restrict__ Kb,
                         const unsigned short* __restrict__ Vb, float* __restrict__ fin){
  __shared__ float Ks[16][260], Vs[16][260];
  int bi = blockIdx.x;
  int chunk = bi % 80; int h = (bi / 80) & 7; int g = bi / 640;
  int s0 = chunk * 256;
  int tid = threadIdx.x;
#pragma unroll
  for (int rr = 0; rr < 8; rr++){
    int idx = rr*256 + tid;
    int s = idx >> 3, d2 = idx & 7;
    size_t gg = ((size_t)(g*HWn + s0 + s))*128 + h*16 + d2*2;
    Ks[d2*2  ][s] = b2f(Kb[gg]);
    Ks[d2*2+1][s] = b2f(Kb[gg+1]);
    Vs[d2*2  ][s] = b2f(Vb[gg]);
    Vs[d2*2+1][s] = b2f(Vb[gg+1]);
  }
  __syncthreads();
  int m = tid >> 4, d = tid & 15;
  float acc = 0.f, ksum = 0.f;
#pragma unroll 4
  for (int s4 = 0; s4 < 64; s4++){
    float4 kv = *(const float4*)&Ks[d][s4*4];
    float4 vv = *(const float4*)&Vs[m][s4*4];
    acc  += kv.x*vv.x + kv.y*vv.y + kv.z*vv.z + kv.w*vv.w;
    ksum += kv.x + kv.y + kv.z + kv.w;
  }
  float* fb = fin + (size_t)(g*8 + h)*272;
  atomicAdd(&fb[tid], acc);
  if (m == 0) atomicAdd(&fb[256 + d], ksum);
}

// ---------------- homography warp + bilinear sample (pixel-major ctx, bf16) ----------------
__global__ __launch_bounds__(128) void k_warp(const unsigned short* __restrict__ ctxref,
     const float* __restrict__ depth, const float* __restrict__ projs,
     unsigned short* __restrict__ ctxsrc){
  int bi = blockIdx.x; int n = bi / HWn; int p = bi - n*HWn;
  int y = p / WW, x = p - y*WW;
  const float* pr = &projs[n*12];
  float d = depth[n*HWn + p];
  float fx = (float)x, fy = (float)y;
  float px = (pr[0]*fx + pr[1]*fy + pr[2])*d + pr[9];
  float py = (pr[3]*fx + pr[4]*fy + pr[5])*d + pr[10];
  float pz = (pr[6]*fx + pr[7]*fy + pr[8])*d + pr[11];
  if (pz == 0.f) pz = 1e-9f;
  float xs = px/pz, ys = py/pz;
  float x0 = floorf(xs), y0 = floorf(ys);
  float wx = xs - x0, wy = ys - y0;
  int c = threadIdx.x;
  float acc = 0.f;
#pragma unroll
  for (int dy = 0; dy < 2; dy++){
    float cy = y0 + dy;
    float wyv = dy ? wy : 1.f - wy;
#pragma unroll
    for (int dx = 0; dx < 2; dx++){
      float cx = x0 + dx;
      float wxv = dx ? wx : 1.f - wx;
      bool valid = (cx >= 0.f) && (cx <= (float)(WW-1)) && (cy >= 0.f) && (cy <= (float)(HH-1));
      int xi = (int)fminf(fmaxf(cx, 0.f), (float)(WW-1));
      int yi = (int)fminf(fmaxf(cy, 0.f), (float)(HH-1));
      float v = b2f(ctxref[((size_t)(n*HWn) + yi*WW + xi)*128 + c]);
      acc += valid ? wxv*wyv*v : 0.f;
    }
  }
  ctxsrc[(size_t)bi*128 + c] = f2b(acc);
}

// ---------------- token build (both streams in one dispatch, z selects) ----------------
__global__ __launch_bounds__(256) void k_build2(const float* __restrict__ featR,
      const float* __restrict__ featS,
      const unsigned short* __restrict__ ctxR, const unsigned short* __restrict__ ctxS,
      unsigned short* __restrict__ outR, unsigned short* __restrict__ outS){
  __shared__ float tile[32][33];
  int tx = threadIdx.x, ty = threadIdx.y;
  int z = blockIdx.z; int b = z & (BN-1); int sel = z >> 1;
  const float* feat = sel ? featS : featR;
  const unsigned short* ctx = sel ? ctxS : ctxR;
  unsigned short* out = sel ? outS : outR;
  int p0 = blockIdx.x*32, c0 = blockIdx.y*32;
  for (int i = ty; i < 32; i += 8)
    tile[i][tx] = feat[((size_t)(b*CD + c0 + i))*HWn + p0 + tx];
  __syncthreads();
  const float LOG1E4_32 = 0.28782313662425572f;  // ln(10000)/32
  for (int r = ty; r < 32; r += 8){
    int p = p0 + r, c = c0 + tx;
    int y = p / WW, x = p - y*WW;
    int i = c >> 2, j = c & 3;
    float dv = __expf(-(float)i * LOG1E4_32);
    float pos = (j < 2) ? (float)(x + 1) : (float)(y + 1);
    float arg = pos * dv;
    float pe = (j & 1) ? cosf(arg) : sinf(arg);
    size_t o = ((size_t)(b*HWn) + p)*128 + c;
    out[o] = f2b(tile[tx][r] + pe + b2f(ctx[o]));
  }
}

// ---------------- host ----------------
extern "C" void kernel_launch(void* const* d_in, const int* in_sizes, int n_in,
                              void* d_out, int out_size, void* d_ws, size_t ws_size,
                              hipStream_t stream) {
  const float* ref_feature = (const float*)d_in[0];
  const float* src_feature = (const float*)d_in[1];
  const float* ref_proj    = (const float*)d_in[2];
  const float* ref_i2w     = (const float*)d_in[4];
  const float* src_i2w     = (const float*)d_in[5];
  const float* depth       = (const float*)d_in[6];
  const float* attn_w      = (const float*)d_in[7];
  const float* attn_b      = (const float*)d_in[8];
  const float* ffn_w1      = (const float*)d_in[9];
  const float* ffn_b1      = (const float*)d_in[10];
  const float* ffn_w2      = (const float*)d_in[11];
  const float* ffn_b2      = (const float*)d_in[12];
  const float* ln_g        = (const float*)d_in[13];
  const float* ln_b        = (const float*)d_in[14];
  const float* rc_w        = (const float*)d_in[15];
  const float* rc_b        = (const float*)d_in[16];
  const float* bn2_g       = (const float*)d_in[17];
  const float* bn2_b       = (const float*)d_in[18];
  const float* cc_w        = (const float*)d_in[19];
  const float* cc_b        = (const float*)d_in[20];
  const float* bn1_g       = (const float*)d_in[21];
  const float* bn1_b       = (const float*)d_in[22];
  const float* fc1_w       = (const float*)d_in[23];
  const float* fc1_b       = (const float*)d_in[24];
  const float* fc2_w       = (const float*)d_in[25];
  const float* fc2_b       = (const float*)d_in[26];
  const float* ser_w       = (const float*)d_in[27];
  const float* ser_b       = (const float*)d_in[28];
  const float* see_w       = (const float*)d_in[29];
  const float* see_b       = (const float*)d_in[30];

  const size_t small_f32 = (size_t)4*2176 + 32 + 256;
  const size_t small_bytes = small_f32*4 + (size_t)540672*2 + 4096;
  const size_t need_batch = (size_t)TOKN*2*8 + small_bytes;   // streams(2)+QKV(6) bf16
  bool BATCH = ws_size >= need_batch;
  const size_t CSEG = BATCH ? 2*TOKN : TOKN;

  char* p = (char*)d_ws;
  unsigned short* Rm = (unsigned short*)p; p += TOKN*2;
  unsigned short* Sm = (unsigned short*)p; p += TOKN*2;      // contiguous after Rm
  unsigned short* QB = (unsigned short*)p; p += CSEG*3*2;
  unsigned short* KB = QB + CSEG;
  unsigned short* VB = QB + 2*CSEG;
  float* KVFIN  = (float*)p; p += (size_t)(BATCH?4:2)*2176*4;
  float* PROJ   = (float*)p; p += 32*4;
  float* GATE   = (float*)p; p += 256*4;
  unsigned short* WT = (unsigned short*)p;

  float* OUT = (float*)d_out;

  k_wconv<<<2113, 256, 0, stream>>>(attn_w, ffn_w1, ffn_w2, cc_w, WT,
      ref_proj, src_i2w, ref_i2w, bn1_g, bn1_b, fc1_w, fc1_b,
      fc2_w, fc2_b, ser_w, ser_b, see_w, see_b, PROJ, GATE);
  k_hmap<<<TT, 128, 0, stream>>>(depth, rc_w, rc_b, bn2_g, bn2_b, GATE, QB);
  k_bgemm6<128,0,0><<<dim3(TT/64, 1), 256, 0, stream>>>(
      QB, QB, 128, WT + 524288, cc_b, 0, nullptr, KB, 0, 128, nullptr, nullptr,
      nullptr, 0);
  k_warp<<<TT, 128, 0, stream>>>(KB, depth, PROJ, VB);
  k_build2<<<dim3(HWn/32, 4, 2*BN), dim3(32, 8), 0, stream>>>(
      ref_feature, src_feature, KB, VB, Rm, Sm);

  auto encode = [&](unsigned short* x, const unsigned short* srcp, int l, int nTok,
                    unsigned short* outBf, float* outF){
    const unsigned short* ATW = WT + (size_t)l*65536;          // [4][128][128]
    const unsigned short* F1T = WT + 262144 + (size_t)l*32768; // [256][128]
    const unsigned short* F2T = WT + 393216 + (size_t)l*32768; // [128][256]
    const float* Bv = attn_b + (size_t)l*512;
    const float* g0 = ln_g + (size_t)l*256; const float* b0 = ln_b + (size_t)l*256;
    int nb = nTok/64, ng = nTok/HWn;
    // QKV in one dispatch: sec0 reads x, secs 1-2 read srcp; block(0,0) zeroes KVFIN
    k_bgemm6<128,2,0><<<dim3(nb, 3), 256, 0, stream>>>(x, srcp, 128, ATW, Bv, 0b011,
                                              nullptr, QB, CSEG, 128, nullptr, nullptr,
                                              KVFIN, ng*2176);
    // KV partials atomically accumulated straight into KVFIN (no reduce dispatch)
    k_kvpart<<<ng*640, 256, 0, stream>>>(KB, VB, KVFIN);
    // fused attn + FFN: out <- LN1(x0 + FFN(x0)), x0 = LN0(x + attn)
    k_fattnffn<<<nb, 256, 0, stream>>>(QB, x, KVFIN, ATW + 3*16384, Bv + 384, g0, b0,
                                       F1T, ffn_b1 + (size_t)l*256, F2T,
                                       ffn_b2 + (size_t)l*128, g0 + 128, b0 + 128,
                                       outBf, outF);
  };

  // layer 0: self
  if (BATCH) encode(Rm, Rm, 0, 2*TT, Rm, nullptr);
  else { encode(Rm, Rm, 0, TT, Rm, nullptr); encode(Sm, Sm, 0, TT, Sm, nullptr); }
  // layer 1: cross (src uses updated ref)
  encode(Rm, Sm, 1, TT, Rm, nullptr); encode(Sm, Rm, 1, TT, Sm, nullptr);
  // layer 2: self
  if (BATCH) encode(Rm, Rm, 2, 2*TT, Rm, nullptr);
  else { encode(Rm, Rm, 2, TT, Rm, nullptr); encode(Sm, Sm, 2, TT, Sm, nullptr); }
  // layer 3: cross — final outputs fused to f32 OUT (no k_tofp32 dispatch)
  encode(Rm, Sm, 3, TT, Rm, OUT);              // Rm still read by next encode's K/V
  encode(Sm, Rm, 3, TT, nullptr, OUT + TOKN);  // Sm unused afterwards: f32 only
}

// Round 36
// 546.230 us; speedup vs baseline: 1.0401x; 1.0094x over previous
//
#include <hip/hip_runtime.h>
#include <math.h>

#define BN 2
#define HH 128
#define WW 160
#define HWn (HH*WW)          // 20480
#define CD 128
#define TT (BN*HWn)          // 40960 tokens per stream
#define TOKN ((size_t)TT*CD) // 5,242,880 elements

typedef __attribute__((ext_vector_type(8))) short bf16x8;
typedef __attribute__((ext_vector_type(4))) float f32x4;
typedef __attribute__((ext_vector_type(4))) unsigned short u16x4;

__device__ __forceinline__ float b2f(unsigned short s){
  unsigned u = ((unsigned)s) << 16;
  return __builtin_bit_cast(float, u);
}
__device__ __forceinline__ unsigned short f2b(float f){
  unsigned u = __builtin_bit_cast(unsigned, f);
  u = (u + 0x7fffu + ((u >> 16) & 1u)) >> 16;   // RNE
  return (unsigned short)u;
}

// ---------------- weight convert + (block 2112) tiny precompute ----------------
__global__ __launch_bounds__(256) void k_wconv(const float* __restrict__ attn_w,
      const float* __restrict__ ffn_w1, const float* __restrict__ ffn_w2,
      const float* __restrict__ cc_w, unsigned short* __restrict__ wt,
      const float* __restrict__ ref_proj, const float* __restrict__ src_i2w,
      const float* __restrict__ cam16,
      const float* __restrict__ bn1_g, const float* __restrict__ bn1_b,
      const float* __restrict__ fc1_w, const float* __restrict__ fc1_b,
      const float* __restrict__ fc2_w, const float* __restrict__ fc2_b,
      const float* __restrict__ ser_w, const float* __restrict__ ser_b,
      const float* __restrict__ see_w, const float* __restrict__ see_b,
      float* __restrict__ projsmall, float* __restrict__ gate){
  if (blockIdx.x == 2112){    // ---- small precompute: proj mats + SE gate ----
    __shared__ float mi[BN][16], t1[BN][128], t2[BN][128];
    int tid = threadIdx.x;
    const float inv_std = rsqrtf(1.0f + 1e-5f);
    if (tid < 32){
      int b = tid >> 4, idx = tid & 15, i = idx >> 2, k = idx & 3;
      float acc = 0.f;
      for (int j = 0; j < 4; j++) acc += ref_proj[b*16 + i*4 + j] * src_i2w[b*16 + j*4 + k];
      if (i < 3 && k < 3) projsmall[b*12 + i*3 + k] = acc;
      if (i < 3 && k == 3) projsmall[b*12 + 9 + i] = acc;
      mi[b][idx] = cam16[b*16 + idx] * inv_std * bn1_g[idx] + bn1_b[idx];
    }
    __syncthreads();
    int b = tid >> 7, c = tid & 127;
    float a = 0.f;
    for (int j = 0; j < 16; j++) a += mi[b][j] * fc1_w[j*128 + c];
    t1[b][c] = fmaxf(a + fc1_b[c], 0.f);
    __syncthreads();
    a = 0.f;
    for (int k = 0; k < 128; k++) a += t1[b][k] * fc2_w[k*128 + c];
    t2[b][c] = a + fc2_b[c];
    __syncthreads();
    a = 0.f;
    for (int k = 0; k < 128; k++) a += t2[b][k] * ser_w[k*128 + c];
    t1[b][c] = fmaxf(a + ser_b[c], 0.f);
    __syncthreads();
    a = 0.f;
    for (int k = 0; k < 128; k++) a += t1[b][k] * see_w[k*128 + c];
    a += see_b[c];
    gate[b*128 + c] = 1.f / (1.f + __expf(-a));
    return;
  }
  int i = blockIdx.x*256 + threadIdx.x;
  float v;
  if (i < 262144){                       // attn: [(l*4+m)][n][k] <- attn_w[lm][k][n]
    int k = i & 127, n = (i >> 7) & 127, lm = i >> 14;
    v = attn_w[((size_t)lm*128 + k)*128 + n];
  } else if (i < 393216){ int j = i - 262144;   // f1t: [l][n<256][k<128]
    int k = j & 127, n = (j >> 7) & 255, l = j >> 15;
    v = ffn_w1[((size_t)l*128 + k)*256 + n];
  } else if (i < 524288){ int j = i - 393216;   // f2t: [l][n<128][k<256]
    int k = j & 255, n = (j >> 8) & 127, l = j >> 15;
    v = ffn_w2[((size_t)l*256 + k)*128 + n];
  } else if (i < 540672){ int j = i - 524288;   // cct: [o][c] <- cc_w[c][o]
    int k = j & 127, n = j >> 7;
    v = cc_w[(size_t)k*128 + n];
  } else return;
  wt[i] = f2b(v);
}

// ---------------- K1: conv3x3(depth) + bn + relu + gate, pixel-major, bf16 out ----------------
__global__ __launch_bounds__(128) void k_hmap(const float* __restrict__ depth,
                       const float* __restrict__ rc_w, const float* __restrict__ rc_b,
                       const float* __restrict__ bn2_g, const float* __restrict__ bn2_b,
                       const float* __restrict__ gate, unsigned short* __restrict__ G){
  int bi = blockIdx.x; int n = bi / HWn; int p = bi - n*HWn;
  int y = p / WW, x = p - y*WW;
  int c = threadIdx.x;
  const float inv_std = rsqrtf(1.f + 1e-5f);
  float acc = 0.f;
#pragma unroll
  for (int ky = 0; ky < 3; ky++){
    int yy = y + ky - 1;
#pragma unroll
    for (int kx = 0; kx < 3; kx++){
      int xx = x + kx - 1;
      float v = (yy >= 0 && yy < HH && xx >= 0 && xx < WW) ? depth[n*HWn + yy*WW + xx] : 0.f;
      acc += v * rc_w[c*9 + ky*3 + kx];
    }
  }
  acc += rc_b[c];
  acc = fmaxf(acc * inv_std * bn2_g[c] + bn2_b[c], 0.f);
  G[(size_t)bi*128 + c] = f2b(acc * gate[n*128 + c]);
}

// ---- bf16 MFMA GEMM (preamble cc projection): 64 tokens/block, XOR-swizzled W ----
template<int K, int ACT, int LN>
__global__ __launch_bounds__(256) void k_bgemm6(
    const unsigned short* __restrict__ A, const unsigned short* __restrict__ A2, int ldA,
    const unsigned short* __restrict__ Wt,
    const float* __restrict__ bias, int amask,
    const unsigned short* __restrict__ resid,
    unsigned short* __restrict__ Cbase, size_t secStride, int ldC,
    const float* __restrict__ lng, const float* __restrict__ lnb){
  __shared__ unsigned short Wl[128*128];
  constexpr int NH = K/128;
  int tid = threadIdx.x;
  int wid = tid >> 6, lane = tid & 63;
  int sec = blockIdx.y;
  const unsigned short* Ab = (sec == 0) ? A : A2;
  const unsigned short* Ws = Wt + (size_t)sec*128*K;
  const float* bs = bias + sec*128;
  unsigned short* C = Cbase + (size_t)sec*secStride;
  int r = lane & 15, ks = lane >> 4;
  size_t t0 = (size_t)blockIdx.x*64 + wid*16;
  const unsigned short* ap = Ab + (t0 + r)*ldA + ks*8;
  f32x4 acc[8] = {};
#pragma unroll
  for (int hh = 0; hh < NH; hh++){
    if (hh > 0) __syncthreads();
#pragma unroll
    for (int i = 0; i < 8; i++){
      int idx = i*256 + tid;
      int row = idx >> 4, c8 = idx & 15;
      int c8s = c8 ^ (row & 7);
      *(bf16x8*)&Wl[row*128 + c8s*8] = *(const bf16x8*)(Ws + (size_t)row*K + hh*128 + c8*8);
    }
    __syncthreads();
#pragma unroll
    for (int j = 0; j < 4; j++){
      bf16x8 a = *(const bf16x8*)(ap + hh*128 + j*32);
#pragma unroll
      for (int f = 0; f < 8; f++){
        int row = f*16 + r;
        int c8s = (j*4 + ks) ^ (row & 7);
        bf16x8 w = *(const bf16x8*)&Wl[row*128 + c8s*8];
        acc[f] = __builtin_amdgcn_mfma_f32_16x16x32_bf16(w, a, acc[f], 0, 0, 0);
      }
    }
  }
  bool act = (amask >> sec) & 1;
  size_t trow = t0 + r;
  float vv[8][4];
#pragma unroll
  for (int f = 0; f < 8; f++){
    float4 bi4 = *(const float4*)&bs[f*16 + 4*ks];
    vv[f][0] = acc[f][0] + bi4.x; vv[f][1] = acc[f][1] + bi4.y;
    vv[f][2] = acc[f][2] + bi4.z; vv[f][3] = acc[f][3] + bi4.w;
    if (resid){
      u16x4 rr = *(const u16x4*)(resid + trow*128 + f*16 + 4*ks);
#pragma unroll
      for (int e = 0; e < 4; e++) vv[f][e] += b2f(rr[e]);
    }
    if (act){
#pragma unroll
      for (int e = 0; e < 4; e++){
        float x = vv[f][e];
        if (ACT == 1) x = fmaxf(x, 0.f);
        if (ACT == 2) x = x > 0.f ? x + 1.f : __expf(x);
        vv[f][e] = x;
      }
    }
  }
  if (LN){
    float s = 0.f;
#pragma unroll
    for (int f = 0; f < 8; f++) s += vv[f][0]+vv[f][1]+vv[f][2]+vv[f][3];
    s += __shfl_xor(s, 16, 64); s += __shfl_xor(s, 32, 64);
    float mean = s * (1.f/128.f);
    float q = 0.f;
#pragma unroll
    for (int f = 0; f < 8; f++)
#pragma unroll
      for (int e = 0; e < 4; e++){ float d = vv[f][e]-mean; q += d*d; }
    q += __shfl_xor(q, 16, 64); q += __shfl_xor(q, 32, 64);
    float rstd = rsqrtf(q*(1.f/128.f) + 1e-5f);
#pragma unroll
    for (int f = 0; f < 8; f++){
      float4 g4 = *(const float4*)&lng[f*16 + 4*ks];
      float4 b4 = *(const float4*)&lnb[f*16 + 4*ks];
      vv[f][0] = (vv[f][0]-mean)*rstd*g4.x + b4.x;
      vv[f][1] = (vv[f][1]-mean)*rstd*g4.y + b4.y;
      vv[f][2] = (vv[f][2]-mean)*rstd*g4.z + b4.z;
      vv[f][3] = (vv[f][3]-mean)*rstd*g4.w + b4.w;
    }
  }
#pragma unroll
  for (int f = 0; f < 8; f++){
    u16x4 o;
#pragma unroll
    for (int e = 0; e < 4; e++) o[e] = f2b(vv[f][e]);
    *(u16x4*)(C + trow*ldC + f*16 + 4*ks) = o;
  }
}

// ---- QKV projection: sec0 -> Q(x); sec1 -> K then V (srcp read once, A-frags in
// regs, Wk/Wv double-staged in same LDS). Bit-identical to the 3-section path.
// Block (0,0) zero-fills zfin (KVFIN) for the following k_kvpart dispatch.
__global__ __launch_bounds__(256) void k_qkv3(
    const unsigned short* __restrict__ X, const unsigned short* __restrict__ S,
    const unsigned short* __restrict__ Wt,   // [q|k|v][128][128]
    const float* __restrict__ bias,          // [q|k|v|o][128]
    unsigned short* __restrict__ Cbase, size_t secStride,
    float* zfin, int zn){
  __shared__ unsigned short Wl[128*128];
  int tid = threadIdx.x;
  int wid = tid >> 6, lane = tid & 63;
  int sec = blockIdx.y;
  if (zfin && blockIdx.x == 0 && sec == 0){
    for (int i = tid; i < zn; i += 256) zfin[i] = 0.f;
  }
  const unsigned short* Ab = (sec == 0) ? X : S;
  int r = lane & 15, ks = lane >> 4;
  size_t t0 = (size_t)blockIdx.x*64 + wid*16;
  const unsigned short* ap = Ab + (t0 + r)*128 + ks*8;
  bf16x8 a4[4];
#pragma unroll
  for (int j = 0; j < 4; j++) a4[j] = *(const bf16x8*)(ap + j*32);
  size_t trow = t0 + r;
  int npass = sec ? 2 : 1;
  for (int pp = 0; pp < npass; pp++){
    int wsec = sec ? (1 + pp) : 0;
    if (pp > 0) __syncthreads();           // previous MFMA reads of Wl done
    const unsigned short* Ws = Wt + (size_t)wsec*16384;
#pragma unroll
    for (int i = 0; i < 8; i++){
      int idx = i*256 + tid;
      int row = idx >> 4, c8 = idx & 15;
      *(bf16x8*)&Wl[row*128 + (c8 ^ (row & 7))*8] =
          *(const bf16x8*)(Ws + (size_t)row*128 + c8*8);
    }
    __syncthreads();
    f32x4 acc[8] = {};
#pragma unroll
    for (int j = 0; j < 4; j++){
#pragma unroll
      for (int f = 0; f < 8; f++){
        int row = f*16 + r;
        bf16x8 w = *(const bf16x8*)&Wl[row*128 + ((j*4 + ks) ^ (row & 7))*8];
        acc[f] = __builtin_amdgcn_mfma_f32_16x16x32_bf16(w, a4[j], acc[f], 0, 0, 0);
      }
    }
    const float* bs = bias + wsec*128;
    unsigned short* C = Cbase + (size_t)wsec*secStride;
    bool act = (wsec < 2);                 // Q,K: elu+1 ; V: none
#pragma unroll
    for (int f = 0; f < 8; f++){
      float4 bi4 = *(const float4*)&bs[f*16 + 4*ks];
      u16x4 o;
#pragma unroll
      for (int e = 0; e < 4; e++){
        float x = acc[f][e] + ((const float*)&bi4)[e];
        if (act) x = x > 0.f ? x + 1.f : __expf(x);
        o[e] = f2b(x);
      }
      *(u16x4*)(C + trow*128 + f*16 + 4*ks) = o;
    }
  }
}

// ---- fused attention+FFN: LN0(X + linattn(Q)@W3 + b3) -> x0; LN1(x0 + FFN(x0)) -> Out
// Out (bf16) nullable; OutF (f32, final-layer fused output) nullable.
__global__ __launch_bounds__(256) void k_fattnffn(
    const unsigned short* __restrict__ Q, const unsigned short* __restrict__ X,
    const float* __restrict__ kvfin, const unsigned short* __restrict__ W3,
    const float* __restrict__ b3, const float* __restrict__ g0, const float* __restrict__ b0,
    const unsigned short* __restrict__ W1t, const float* __restrict__ b1,
    const unsigned short* __restrict__ W2t, const float* __restrict__ b2,
    const float* __restrict__ g1, const float* __restrict__ lb1,
    unsigned short* __restrict__ Out, float* __restrict__ OutF){
  __shared__ unsigned short Wl[128*128];   // 32KB staged weights
  __shared__ unsigned short UB[64*136];    // 17KB: V -> x0 -> H (per-half)
  __shared__ float ksums[8][16];
  int tid = threadIdx.x;
  size_t tb = (size_t)blockIdx.x*64;
  int g = (int)(tb / HWn);
  const float* kvb = kvfin + g*2176;
  // ---- stage blockdiag(KV) ----
  {
    int row = tid >> 1, half = tid & 1;
    int h = row >> 4, m = row & 15;
    int swz = row & 7;
#pragma unroll
    for (int c8i = 0; c8i < 8; c8i++){
      int c8 = half*8 + c8i;
      bf16x8 val = {};
      if ((c8 >> 1) == h){
        int d0 = (c8 & 1)*8;
        const float* src = kvb + h*272 + m*16 + d0;
#pragma unroll
        for (int e = 0; e < 8; e++) ((unsigned short*)&val)[e] = f2b(src[e]);
      }
      *(bf16x8*)&Wl[row*128 + (c8 ^ swz)*8] = val;
    }
  }
  if (tid < 128) ksums[tid >> 4][tid & 15] = kvb[(tid >> 4)*272 + 256 + (tid & 15)];
  __syncthreads();
  int wid = tid >> 6, lane = tid & 63;
  int r = lane & 15, ks = lane >> 4;
  int tl = wid*16 + r;
  size_t trow = tb + tl;
  // ---- num MFMA + den partials ----
  f32x4 acc[8] = {};
  float part0 = 0.f, part1 = 0.f, part2 = 0.f, part3 = 0.f;
  int myp = ks >> 1;
  int dlo = (ks & 1)*8;
#pragma unroll
  for (int j = 0; j < 4; j++){
    bf16x8 a = *(const bf16x8*)(Q + trow*128 + j*32 + ks*8);
    float pj = 0.f;
    int hj = 2*j + myp;
#pragma unroll
    for (int e = 0; e < 8; e++)
      pj += b2f(((unsigned short*)&a)[e]) * ksums[hj][dlo + e];
    if (j == 0) part0 = pj; else if (j == 1) part1 = pj;
    else if (j == 2) part2 = pj; else part3 = pj;
#pragma unroll
    for (int f = 0; f < 8; f++){
      int row = f*16 + r;
      int c8s = (j*4 + ks) ^ (row & 7);
      bf16x8 w = *(const bf16x8*)&Wl[row*128 + c8s*8];
      acc[f] = __builtin_amdgcn_mfma_f32_16x16x32_bf16(w, a, acc[f], 0, 0, 0);
    }
  }
  float full0 = part0 + __shfl_xor(part0, 16, 64);
  float full1 = part1 + __shfl_xor(part1, 16, 64);
  float full2 = part2 + __shfl_xor(part2, 16, 64);
  float full3 = part3 + __shfl_xor(part3, 16, 64);
  float oth0 = __shfl_xor(full0, 32, 64);
  float oth1 = __shfl_xor(full1, 32, 64);
  float oth2 = __shfl_xor(full2, 32, 64);
  float oth3 = __shfl_xor(full3, 32, 64);
  // V -> UB
#pragma unroll
  for (int f = 0; f < 8; f++){
    float fl, ot;
    if (f < 2){ fl = full0; ot = oth0; } else if (f < 4){ fl = full1; ot = oth1; }
    else if (f < 6){ fl = full2; ot = oth2; } else { fl = full3; ot = oth3; }
    float den = ((f & 1) == myp) ? fl : ot;
    float rc = 1.f / (den + 1e-6f);
    u16x4 o;
#pragma unroll
    for (int e = 0; e < 4; e++) o[e] = f2b(acc[f][e] * rc);
    *(u16x4*)&UB[tl*136 + f*16 + 4*ks] = o;
  }
  __syncthreads();
  // ---- stage W3 ----
#pragma unroll
  for (int i = 0; i < 8; i++){
    int idx = i*256 + tid;
    int row = idx >> 4, c8 = idx & 15;
    int c8s = c8 ^ (row & 7);
    *(bf16x8*)&Wl[row*128 + c8s*8] = *(const bf16x8*)(W3 + (size_t)row*128 + c8*8);
  }
  __syncthreads();
  // ---- out-proj MFMA + residual + LN0 -> x0 (regs + UB) ----
  f32x4 acc2[8] = {};
#pragma unroll
  for (int j = 0; j < 4; j++){
    bf16x8 a = *(const bf16x8*)&UB[tl*136 + j*32 + ks*8];
#pragma unroll
    for (int f = 0; f < 8; f++){
      int row = f*16 + r;
      int c8s = (j*4 + ks) ^ (row & 7);
      bf16x8 w = *(const bf16x8*)&Wl[row*128 + c8s*8];
      acc2[f] = __builtin_amdgcn_mfma_f32_16x16x32_bf16(w, a, acc2[f], 0, 0, 0);
    }
  }
  float vv[8][4];
#pragma unroll
  for (int f = 0; f < 8; f++){
    float4 bi4 = *(const float4*)&b3[f*16 + 4*ks];
    u16x4 rr = *(const u16x4*)(X + trow*128 + f*16 + 4*ks);
    vv[f][0] = acc2[f][0] + bi4.x + b2f(rr[0]);
    vv[f][1] = acc2[f][1] + bi4.y + b2f(rr[1]);
    vv[f][2] = acc2[f][2] + bi4.z + b2f(rr[2]);
    vv[f][3] = acc2[f][3] + bi4.w + b2f(rr[3]);
  }
  {
    float s = 0.f;
#pragma unroll
    for (int f = 0; f < 8; f++) s += vv[f][0]+vv[f][1]+vv[f][2]+vv[f][3];
    s += __shfl_xor(s, 16, 64); s += __shfl_xor(s, 32, 64);
    float mean = s * (1.f/128.f);
    float q = 0.f;
#pragma unroll
    for (int f = 0; f < 8; f++)
#pragma unroll
      for (int e = 0; e < 4; e++){ float d = vv[f][e]-mean; q += d*d; }
    q += __shfl_xor(q, 16, 64); q += __shfl_xor(q, 32, 64);
    float rstd = rsqrtf(q*(1.f/128.f) + 1e-5f);
#pragma unroll
    for (int f = 0; f < 8; f++){
      float4 g4 = *(const float4*)&g0[f*16 + 4*ks];
      float4 b4 = *(const float4*)&b0[f*16 + 4*ks];
      vv[f][0] = (vv[f][0]-mean)*rstd*g4.x + b4.x;
      vv[f][1] = (vv[f][1]-mean)*rstd*g4.y + b4.y;
      vv[f][2] = (vv[f][2]-mean)*rstd*g4.z + b4.z;
      vv[f][3] = (vv[f][3]-mean)*rstd*g4.w + b4.w;
    }
  }
  u16x4 xr[8];                 // x0 kept in regs for FFN2 residual
#pragma unroll
  for (int f = 0; f < 8; f++){
#pragma unroll
    for (int e = 0; e < 4; e++) xr[f][e] = f2b(vv[f][e]);
    *(u16x4*)&UB[tl*136 + f*16 + 4*ks] = xr[f];
  }
  __syncthreads();             // all x0 writes done; W3 readers done
  // ---- load FFN input fragments (x0) into regs; UB may then hold H ----
  bf16x8 areg[4];
#pragma unroll
  for (int j = 0; j < 4; j++) areg[j] = *(const bf16x8*)&UB[tl*136 + j*32 + ks*8];
  // ---- interleaved FFN: for each half: W1h->H, W2k·H accumulate ----
  f32x4 acc3[8] = {};
#pragma unroll
  for (int hh = 0; hh < 2; hh++){
    if (hh > 0) __syncthreads();           // previous Wl readers (W2k0 MFMA) done
    // stage W1 half hh
#pragma unroll
    for (int i = 0; i < 8; i++){
      int idx = i*256 + tid;
      int row = idx >> 4, c8 = idx & 15;
      *(bf16x8*)&Wl[row*128 + (c8 ^ (row & 7))*8] =
          *(const bf16x8*)(W1t + (size_t)(hh*128 + row)*128 + c8*8);
    }
    __syncthreads();
    f32x4 accf[8] = {};
#pragma unroll
    for (int j = 0; j < 4; j++){
#pragma unroll
      for (int f = 0; f < 8; f++){
        int row = f*16 + r;
        int c8s = (j*4 + ks) ^ (row & 7);
        bf16x8 w = *(const bf16x8*)&Wl[row*128 + c8s*8];
        accf[f] = __builtin_amdgcn_mfma_f32_16x16x32_bf16(w, areg[j], accf[f], 0, 0, 0);
      }
    }
#pragma unroll
    for (int f = 0; f < 8; f++){
      float4 bi4 = *(const float4*)&b1[hh*128 + f*16 + 4*ks];
      u16x4 o;
      o[0] = f2b(fmaxf(accf[f][0] + bi4.x, 0.f));
      o[1] = f2b(fmaxf(accf[f][1] + bi4.y, 0.f));
      o[2] = f2b(fmaxf(accf[f][2] + bi4.z, 0.f));
      o[3] = f2b(fmaxf(accf[f][3] + bi4.w, 0.f));
      *(u16x4*)&UB[tl*136 + f*16 + 4*ks] = o;    // H half (own rows)
    }
    __syncthreads();                       // W1 readers done before W2 staging
    // stage W2 k-half hh
#pragma unroll
    for (int i = 0; i < 8; i++){
      int idx = i*256 + tid;
      int row = idx >> 4, c8 = idx & 15;
      *(bf16x8*)&Wl[row*128 + (c8 ^ (row & 7))*8] =
          *(const bf16x8*)(W2t + (size_t)row*256 + hh*128 + c8*8);
    }
    __syncthreads();
#pragma unroll
    for (int j = 0; j < 4; j++){
      bf16x8 a = *(const bf16x8*)&UB[tl*136 + j*32 + ks*8];
#pragma unroll
      for (int f = 0; f < 8; f++){
        int row = f*16 + r;
        int c8s = (j*4 + ks) ^ (row & 7);
        bf16x8 w = *(const bf16x8*)&Wl[row*128 + c8s*8];
        acc3[f] = __builtin_amdgcn_mfma_f32_16x16x32_bf16(w, a, acc3[f], 0, 0, 0);
      }
    }
  }
  // ---- epilogue: + b2 + residual(x0 regs) + LN1 -> Out / OutF ----
#pragma unroll
  for (int f = 0; f < 8; f++){
    float4 bi4 = *(const float4*)&b2[f*16 + 4*ks];
    vv[f][0] = acc3[f][0] + bi4.x + b2f(xr[f][0]);
    vv[f][1] = acc3[f][1] + bi4.y + b2f(xr[f][1]);
    vv[f][2] = acc3[f][2] + bi4.z + b2f(xr[f][2]);
    vv[f][3] = acc3[f][3] + bi4.w + b2f(xr[f][3]);
  }
  float s = 0.f;
#pragma unroll
  for (int f = 0; f < 8; f++) s += vv[f][0]+vv[f][1]+vv[f][2]+vv[f][3];
  s += __shfl_xor(s, 16, 64); s += __shfl_xor(s, 32, 64);
  float mean = s * (1.f/128.f);
  float q = 0.f;
#pragma unroll
  for (int f = 0; f < 8; f++)
#pragma unroll
    for (int e = 0; e < 4; e++){ float d = vv[f][e]-mean; q += d*d; }
  q += __shfl_xor(q, 16, 64); q += __shfl_xor(q, 32, 64);
  float rstd = rsqrtf(q*(1.f/128.f) + 1e-5f);
#pragma unroll
  for (int f = 0; f < 8; f++){
    float4 g4 = *(const float4*)&g1[f*16 + 4*ks];
    float4 b4 = *(const float4*)&lb1[f*16 + 4*ks];
    float o0 = (vv[f][0]-mean)*rstd*g4.x + b4.x;
    float o1 = (vv[f][1]-mean)*rstd*g4.y + b4.y;
    float o2 = (vv[f][2]-mean)*rstd*g4.z + b4.z;
    float o3 = (vv[f][3]-mean)*rstd*g4.w + b4.w;
    if (Out){
      u16x4 o = { f2b(o0), f2b(o1), f2b(o2), f2b(o3) };
      *(u16x4*)(Out + trow*128 + f*16 + 4*ks) = o;
    }
    if (OutF){
      float4 of = { o0, o1, o2, o3 };
      *(float4*)(OutF + trow*128 + f*16 + 4*ks) = of;
    }
  }
}

// ---------------- KV partial: transposed staging, atomic reduce into KVFIN ----------------
__global__ __launch_bounds__(256) void k_kvpart(const unsigned short* __restrict__ Kb,
                         const unsigned short* __restrict__ Vb, float* __restrict__ fin){
  __shared__ float Ks[16][260], Vs[16][260];
  int bi = blockIdx.x;
  int chunk = bi % 80; int h = (bi / 80) & 7; int g = bi / 640;
  int s0 = chunk * 256;
  int tid = threadIdx.x;
#pragma unroll
  for (int rr = 0; rr < 8; rr++){
    int idx = rr*256 + tid;
    int s = idx >> 3, d2 = idx & 7;
    size_t gg = ((size_t)(g*HWn + s0 + s))*128 + h*16 + d2*2;
    Ks[d2*2  ][s] = b2f(Kb[gg]);
    Ks[d2*2+1][s] = b2f(Kb[gg+1]);
    Vs[d2*2  ][s] = b2f(Vb[gg]);
    Vs[d2*2+1][s] = b2f(Vb[gg+1]);
  }
  __syncthreads();
  int m = tid >> 4, d = tid & 15;
  float acc = 0.f, ksum = 0.f;
#pragma unroll 4
  for (int s4 = 0; s4 < 64; s4++){
    float4 kv = *(const float4*)&Ks[d][s4*4];
    float4 vv = *(const float4*)&Vs[m][s4*4];
    acc  += kv.x*vv.x + kv.y*vv.y + kv.z*vv.z + kv.w*vv.w;
    ksum += kv.x + kv.y + kv.z + kv.w;
  }
  float* fb = fin + (size_t)(g*8 + h)*272;
  atomicAdd(&fb[tid], acc);
  if (m == 0) atomicAdd(&fb[256 + d], ksum);
}

// ---------------- homography warp + bilinear sample (pixel-major ctx, bf16) ----------------
__global__ __launch_bounds__(128) void k_warp(const unsigned short* __restrict__ ctxref,
     const float* __restrict__ depth, const float* __restrict__ projs,
     unsigned short* __restrict__ ctxsrc){
  int bi = blockIdx.x; int n = bi / HWn; int p = bi - n*HWn;
  int y = p / WW, x = p - y*WW;
  const float* pr = &projs[n*12];
  float d = depth[n*HWn + p];
  float fx = (float)x, fy = (float)y;
  float px = (pr[0]*fx + pr[1]*fy + pr[2])*d + pr[9];
  float py = (pr[3]*fx + pr[4]*fy + pr[5])*d + pr[10];
  float pz = (pr[6]*fx + pr[7]*fy + pr[8])*d + pr[11];
  if (pz == 0.f) pz = 1e-9f;
  float xs = px/pz, ys = py/pz;
  float x0 = floorf(xs), y0 = floorf(ys);
  float wx = xs - x0, wy = ys - y0;
  int c = threadIdx.x;
  float acc = 0.f;
#pragma unroll
  for (int dy = 0; dy < 2; dy++){
    float cy = y0 + dy;
    float wyv = dy ? wy : 1.f - wy;
#pragma unroll
    for (int dx = 0; dx < 2; dx++){
      float cx = x0 + dx;
      float wxv = dx ? wx : 1.f - wx;
      bool valid = (cx >= 0.f) && (cx <= (float)(WW-1)) && (cy >= 0.f) && (cy <= (float)(HH-1));
      int xi = (int)fminf(fmaxf(cx, 0.f), (float)(WW-1));
      int yi = (int)fminf(fmaxf(cy, 0.f), (float)(HH-1));
      float v = b2f(ctxref[((size_t)(n*HWn) + yi*WW + xi)*128 + c]);
      acc += valid ? wxv*wyv*v : 0.f;
    }
  }
  ctxsrc[(size_t)bi*128 + c] = f2b(acc);
}

// ---------------- token build (both streams in one dispatch, z selects) ----------------
__global__ __launch_bounds__(256) void k_build2(const float* __restrict__ featR,
      const float* __restrict__ featS,
      const unsigned short* __restrict__ ctxR, const unsigned short* __restrict__ ctxS,
      unsigned short* __restrict__ outR, unsigned short* __restrict__ outS){
  __shared__ float tile[32][33];
  int tx = threadIdx.x, ty = threadIdx.y;
  int z = blockIdx.z; int b = z & (BN-1); int sel = z >> 1;
  const float* feat = sel ? featS : featR;
  const unsigned short* ctx = sel ? ctxS : ctxR;
  unsigned short* out = sel ? outS : outR;
  int p0 = blockIdx.x*32, c0 = blockIdx.y*32;
  for (int i = ty; i < 32; i += 8)
    tile[i][tx] = feat[((size_t)(b*CD + c0 + i))*HWn + p0 + tx];
  __syncthreads();
  const float LOG1E4_32 = 0.28782313662425572f;  // ln(10000)/32
  for (int r = ty; r < 32; r += 8){
    int p = p0 + r, c = c0 + tx;
    int y = p / WW, x = p - y*WW;
    int i = c >> 2, j = c & 3;
    float dv = __expf(-(float)i * LOG1E4_32);
    float pos = (j < 2) ? (float)(x + 1) : (float)(y + 1);
    float arg = pos * dv;
    float pe = (j & 1) ? cosf(arg) : sinf(arg);
    size_t o = ((size_t)(b*HWn) + p)*128 + c;
    out[o] = f2b(tile[tx][r] + pe + b2f(ctx[o]));
  }
}

// ---------------- host ----------------
extern "C" void kernel_launch(void* const* d_in, const int* in_sizes, int n_in,
                              void* d_out, int out_size, void* d_ws, size_t ws_size,
                              hipStream_t stream) {
  const float* ref_feature = (const float*)d_in[0];
  const float* src_feature = (const float*)d_in[1];
  const float* ref_proj    = (const float*)d_in[2];
  const float* ref_i2w     = (const float*)d_in[4];
  const float* src_i2w     = (const float*)d_in[5];
  const float* depth       = (const float*)d_in[6];
  const float* attn_w      = (const float*)d_in[7];
  const float* attn_b      = (const float*)d_in[8];
  const float* ffn_w1      = (const float*)d_in[9];
  const float* ffn_b1      = (const float*)d_in[10];
  const float* ffn_w2      = (const float*)d_in[11];
  const float* ffn_b2      = (const float*)d_in[12];
  const float* ln_g        = (const float*)d_in[13];
  const float* ln_b        = (const float*)d_in[14];
  const float* rc_w        = (const float*)d_in[15];
  const float* rc_b        = (const float*)d_in[16];
  const float* bn2_g       = (const float*)d_in[17];
  const float* bn2_b       = (const float*)d_in[18];
  const float* cc_w        = (const float*)d_in[19];
  const float* cc_b        = (const float*)d_in[20];
  const float* bn1_g       = (const float*)d_in[21];
  const float* bn1_b       = (const float*)d_in[22];
  const float* fc1_w       = (const float*)d_in[23];
  const float* fc1_b       = (const float*)d_in[24];
  const float* fc2_w       = (const float*)d_in[25];
  const float* fc2_b       = (const float*)d_in[26];
  const float* ser_w       = (const float*)d_in[27];
  const float* ser_b       = (const float*)d_in[28];
  const float* see_w       = (const float*)d_in[29];
  const float* see_b       = (const float*)d_in[30];

  const size_t small_f32 = (size_t)4*2176 + 32 + 256;
  const size_t small_bytes = small_f32*4 + (size_t)540672*2 + 4096;
  const size_t need_batch = (size_t)TOKN*2*8 + small_bytes;   // streams(2)+QKV(6) bf16
  bool BATCH = ws_size >= need_batch;
  const size_t CSEG = BATCH ? 2*TOKN : TOKN;

  char* p = (char*)d_ws;
  unsigned short* Rm = (unsigned short*)p; p += TOKN*2;
  unsigned short* Sm = (unsigned short*)p; p += TOKN*2;      // contiguous after Rm
  unsigned short* QB = (unsigned short*)p; p += CSEG*3*2;
  unsigned short* KB = QB + CSEG;
  unsigned short* VB = QB + 2*CSEG;
  float* KVFIN  = (float*)p; p += (size_t)(BATCH?4:2)*2176*4;
  float* PROJ   = (float*)p; p += 32*4;
  float* GATE   = (float*)p; p += 256*4;
  unsigned short* WT = (unsigned short*)p;

  float* OUT = (float*)d_out;

  k_wconv<<<2113, 256, 0, stream>>>(attn_w, ffn_w1, ffn_w2, cc_w, WT,
      ref_proj, src_i2w, ref_i2w, bn1_g, bn1_b, fc1_w, fc1_b,
      fc2_w, fc2_b, ser_w, ser_b, see_w, see_b, PROJ, GATE);
  k_hmap<<<TT, 128, 0, stream>>>(depth, rc_w, rc_b, bn2_g, bn2_b, GATE, QB);
  k_bgemm6<128,0,0><<<dim3(TT/64, 1), 256, 0, stream>>>(
      QB, QB, 128, WT + 524288, cc_b, 0, nullptr, KB, 0, 128, nullptr, nullptr);
  k_warp<<<TT, 128, 0, stream>>>(KB, depth, PROJ, VB);
  k_build2<<<dim3(HWn/32, 4, 2*BN), dim3(32, 8), 0, stream>>>(
      ref_feature, src_feature, KB, VB, Rm, Sm);

  auto encode = [&](unsigned short* x, const unsigned short* srcp, int l, int nTok,
                    unsigned short* outBf, float* outF){
    const unsigned short* ATW = WT + (size_t)l*65536;          // [4][128][128]
    const unsigned short* F1T = WT + 262144 + (size_t)l*32768; // [256][128]
    const unsigned short* F2T = WT + 393216 + (size_t)l*32768; // [128][256]
    const float* Bv = attn_b + (size_t)l*512;
    const float* g0 = ln_g + (size_t)l*256; const float* b0 = ln_b + (size_t)l*256;
    int nb = nTok/64, ng = nTok/HWn;
    // QKV in 2 sections: sec0 -> Q(x); sec1 -> K+V (srcp read once). Blk(0,0) zeroes KVFIN.
    k_qkv3<<<dim3(nb, 2), 256, 0, stream>>>(x, srcp, ATW, Bv, QB, CSEG,
                                            KVFIN, ng*2176);
    // KV partials atomically accumulated straight into KVFIN (no reduce dispatch)
    k_kvpart<<<ng*640, 256, 0, stream>>>(KB, VB, KVFIN);
    // fused attn + FFN: out <- LN1(x0 + FFN(x0)), x0 = LN0(x + attn)
    k_fattnffn<<<nb, 256, 0, stream>>>(QB, x, KVFIN, ATW + 3*16384, Bv + 384, g0, b0,
                                       F1T, ffn_b1 + (size_t)l*256, F2T,
                                       ffn_b2 + (size_t)l*128, g0 + 128, b0 + 128,
                                       outBf, outF);
  };

  // layer 0: self
  if (BATCH) encode(Rm, Rm, 0, 2*TT, Rm, nullptr);
  else { encode(Rm, Rm, 0, TT, Rm, nullptr); encode(Sm, Sm, 0, TT, Sm, nullptr); }
  // layer 1: cross (src uses updated ref)
  encode(Rm, Sm, 1, TT, Rm, nullptr); encode(Sm, Rm, 1, TT, Sm, nullptr);
  // layer 2: self
  if (BATCH) encode(Rm, Rm, 2, 2*TT, Rm, nullptr);
  else { encode(Rm, Rm, 2, TT, Rm, nullptr); encode(Sm, Sm, 2, TT, Sm, nullptr); }
  // layer 3: cross — final outputs fused to f32 OUT (no k_tofp32 dispatch)
  encode(Rm, Sm, 3, TT, Rm, OUT);              // Rm still read by next encode's K/V
  encode(Sm, Rm, 3, TT, nullptr, OUT + TOKN);  // Sm unused afterwards: f32 only
}